// Round 7
// baseline (374.656 us; speedup 1.0000x reference)
//
#include <hip/hip_runtime.h>
#include <hip/hip_bf16.h>

#define NU 200000
#define NM 80000
#define NT 280000   // NU + NM
#define HD 64
#define FM 20

#define BSHIFT 10
#define NBUCK ((NT + 1023) >> 10)   // 274 buckets of 1024 nodes
#define SCHUNK 4096                 // edges per hist/scatter block

#define PD8 9        // padded LDS row: 9 x short8 slots (144B, odd -> conflict-free)

typedef __attribute__((ext_vector_type(8))) short short8;
typedef __attribute__((ext_vector_type(4))) float floatx4;

__device__ __forceinline__ float bfu2f(unsigned short u) {
    union { unsigned int u; float f; } c; c.u = ((unsigned int)u) << 16; return c.f;
}

__device__ __forceinline__ unsigned short f2bf_raw(float f) {
    union { float f; unsigned int u; } c; c.f = f;
    unsigned int u = c.u + 0x7FFFu + ((c.u >> 16) & 1u);   // round-nearest-even
    return (unsigned short)(u >> 16);
}

__device__ __forceinline__ float ldf(const void* p, long i, int isbf) {
    return isbf ? bfu2f(((const unsigned short*)p)[i]) : ((const float*)p)[i];
}
__device__ __forceinline__ int ldidx(const int* p, long j, int is64) {
    return is64 ? p[2 * j] : p[j];
}

// ---------------- runtime dtype probe -> flags[0]=isbf16, flags[1]=isint64
__global__ void probe_kernel(const void* user_emb, const int* ei, int* flags) {
    int t = threadIdx.x;
    int bad = 0;
    for (int i = t; i < 128; i += 64) {
        unsigned short h = ((const unsigned short*)user_emb)[i];
        unsigned int e = (h >> 7) & 0xFF;
        if (e >= 135) bad = 1;               // |x| >= 256, or Inf/NaN -> not real bf16
    }
    unsigned long long mf = __ballot(bad != 0);
    int odd_nonzero = 0;
    if (t < 16 && ei[2 * t + 1] != 0) odd_nonzero = 1;
    unsigned long long mi = __ballot(odd_nonzero != 0);
    if (t == 0) {
        flags[0] = (mf == 0) ? 1 : 0;
        flags[1] = (mi == 0) ? 1 : 0;
    }
}

// ---------------- prep weights: one block converts/copies all layer weights to
// bf16 (+ f32 biases) in workspace once; sage_layer then reads them straight
// from global (16KB total -> L1-hot) instead of staging into LDS per block.
__global__ __launch_bounds__(512) void prep_weights(
    const void* __restrict__ W1l, const void* __restrict__ b1, const void* __restrict__ W1r,
    const void* __restrict__ W2l, const void* __restrict__ b2, const void* __restrict__ W2r,
    unsigned short* __restrict__ wsW,   // 4 x 4096 shorts: W1l, W1r, W2l, W2r
    float* __restrict__ wsb,            // 2 x 64 floats: b1, b2
    const int* __restrict__ flags)
{
    int t = threadIdx.x;                // 512 threads x short8 = 4096 elems exactly
    int isbf = flags[0];
    const void* srcs[4] = {W1l, W1r, W2l, W2r};
    #pragma unroll
    for (int w = 0; w < 4; ++w) {
        unsigned short* dst = wsW + w * (HD * HD);
        if (isbf) {
            ((short8*)dst)[t] = ((const short8*)srcs[w])[t];
        } else {
            floatx4 a = ((const floatx4*)srcs[w])[2 * t];
            floatx4 b = ((const floatx4*)srcs[w])[2 * t + 1];
            short8 r;
            r[0]=(short)f2bf_raw(a[0]); r[1]=(short)f2bf_raw(a[1]); r[2]=(short)f2bf_raw(a[2]); r[3]=(short)f2bf_raw(a[3]);
            r[4]=(short)f2bf_raw(b[0]); r[5]=(short)f2bf_raw(b[1]); r[6]=(short)f2bf_raw(b[2]); r[7]=(short)f2bf_raw(b[3]);
            ((short8*)dst)[t] = r;
        }
    }
    if (t < HD) {
        wsb[t]      = ldf(b1, t, isbf);
        wsb[HD + t] = ldf(b2, t, isbf);
    }
}

// ---------------- prep A: user rows. In bf16 mode this copy is UNUSED (sage
// layer 1 reads user_emb directly) -> early-exit. fp32 mode converts as before.
__global__ __launch_bounds__(256) void prep_user(
    const void* __restrict__ user_emb,
    unsigned short* __restrict__ xb,
    const int* __restrict__ flags)
{
    if (flags[0]) return;               // bf16: no copy needed
    long t = (long)blockIdx.x * 256 + threadIdx.x;        // t < NU*HD/8 = 1.6M exactly
    floatx4 a = ((const floatx4*)user_emb)[2 * t];
    floatx4 b = ((const floatx4*)user_emb)[2 * t + 1];
    short8 r;
    r[0] = (short)f2bf_raw(a[0]); r[1] = (short)f2bf_raw(a[1]);
    r[2] = (short)f2bf_raw(a[2]); r[3] = (short)f2bf_raw(a[3]);
    r[4] = (short)f2bf_raw(b[0]); r[5] = (short)f2bf_raw(b[1]);
    r[6] = (short)f2bf_raw(b[2]); r[7] = (short)f2bf_raw(b[3]);
    ((short8*)xb)[t] = r;
}

// ---------------- prep B: movie rows, latency-optimized (unchanged).
__global__ __launch_bounds__(256) void prep_movie(
    const void* __restrict__ movie_x,
    const void* __restrict__ movie_emb,
    const void* __restrict__ lin_W,
    const void* __restrict__ lin_b,
    unsigned short* __restrict__ xb,
    const int* __restrict__ flags)
{
    int isbf = flags[0];
    int tid = threadIdx.x;
    int lane = tid & 63;
    int wave = blockIdx.x * 4 + (tid >> 6);
    int m0 = __builtin_amdgcn_readfirstlane(wave << 2);   // 4 movies per wave
    if (m0 >= NM) return;

    float wr[FM];
    if (isbf) {
        const unsigned int* p = (const unsigned int*)((const unsigned short*)lin_W + (long)lane * FM);
        #pragma unroll
        for (int i = 0; i < FM / 2; ++i) {
            unsigned int u = p[i];
            wr[2 * i]     = bfu2f((unsigned short)(u & 0xFFFFu));
            wr[2 * i + 1] = bfu2f((unsigned short)(u >> 16));
        }
    } else {
        const floatx4* p = (const floatx4*)((const float*)lin_W + (long)lane * FM);
        #pragma unroll
        for (int i = 0; i < FM / 4; ++i) {
            floatx4 v = p[i];
            wr[4 * i] = v[0]; wr[4 * i + 1] = v[1]; wr[4 * i + 2] = v[2]; wr[4 * i + 3] = v[3];
        }
    }
    float bias = ldf(lin_b, lane, isbf);

    #pragma unroll
    for (int mm = 0; mm < 4; ++mm) {
        int m = m0 + mm;
        float a0 = bias + ldf(movie_emb, (long)m * HD + lane, isbf);
        float a1 = 0.f, a2 = 0.f, a3 = 0.f;
        if (isbf) {
            const unsigned int* mr = (const unsigned int*)((const unsigned short*)movie_x + (long)m * FM);
            #pragma unroll
            for (int kk = 0; kk < FM / 2; ++kk) {
                unsigned int u = mr[kk];
                float x0 = bfu2f((unsigned short)(u & 0xFFFFu));
                float x1 = bfu2f((unsigned short)(u >> 16));
                if (kk & 1) { a2 += x0 * wr[2 * kk]; a3 += x1 * wr[2 * kk + 1]; }
                else        { a0 += x0 * wr[2 * kk]; a1 += x1 * wr[2 * kk + 1]; }
            }
        } else {
            const float* mr = (const float*)movie_x + (long)m * FM;
            #pragma unroll
            for (int k = 0; k < FM; k += 4) {
                a0 += mr[k]     * wr[k];
                a1 += mr[k + 1] * wr[k + 1];
                a2 += mr[k + 2] * wr[k + 2];
                a3 += mr[k + 3] * wr[k + 3];
            }
        }
        xb[(long)(NU + m) * HD + lane] = f2bf_raw((a0 + a1) + (a2 + a3));
    }
}

// ---------------- CSR build v3: atomic-free scatter via 2D histogram scan ----
__global__ __launch_bounds__(512) void blk_hist(
    const int* __restrict__ ei, int E,
    int* __restrict__ blkhist,
    const int* __restrict__ flags)
{
    __shared__ int h[NBUCK];
    int tid = threadIdx.x;
    for (int i = tid; i < NBUCK; i += 512) h[i] = 0;
    __syncthreads();
    int is64 = flags[1];
    long e0 = (long)blockIdx.x * SCHUNK;
    long e1 = e0 + SCHUNK; if (e1 > E) e1 = E;
    for (long j = e0 + tid; j < e1; j += 512) {
        int d = ldidx(ei, (long)E + j, is64);
        atomicAdd(&h[d >> BSHIFT], 1);
    }
    __syncthreads();
    long obase = (long)blockIdx.x * NBUCK;
    for (int i = tid; i < NBUCK; i += 512) blkhist[obase + i] = h[i];
}

__global__ __launch_bounds__(256) void col_scan(
    int* __restrict__ blkhist, int NSB,
    int* __restrict__ bcnt)
{
    __shared__ int larr[2048];
    __shared__ int lsum[256];
    int b = blockIdx.x;
    int t = threadIdx.x;
    for (int i = t; i < NSB; i += 256) larr[i] = blkhist[(long)i * NBUCK + b];
    __syncthreads();
    int C = (NSB + 255) >> 8;
    int beg = t * C;
    int end = beg + C; if (end > NSB) end = NSB; if (beg > NSB) beg = NSB;
    int s = 0;
    for (int i = beg; i < end; ++i) s += larr[i];
    lsum[t] = s;
    __syncthreads();
    for (int off = 1; off < 256; off <<= 1) {
        int v = lsum[t];
        if (t >= off) v += lsum[t - off];
        __syncthreads();
        lsum[t] = v;
        __syncthreads();
    }
    int run = (t == 0) ? 0 : lsum[t - 1];
    for (int i = beg; i < end; ++i) {
        int v = larr[i];
        blkhist[(long)i * NBUCK + b] = run;   // exclusive offset of block i in bucket b
        run += v;
    }
    if (t == 0) bcnt[b] = lsum[255];
}

__global__ __launch_bounds__(256) void bucket_scan(
    const int* __restrict__ bcnt, int* __restrict__ bstart, int E)
{
    __shared__ int s[256];
    int t = threadIdx.x;
    int a0 = (2 * t     < NBUCK) ? bcnt[2 * t]     : 0;
    int a1 = (2 * t + 1 < NBUCK) ? bcnt[2 * t + 1] : 0;
    s[t] = a0 + a1;
    __syncthreads();
    for (int off = 1; off < 256; off <<= 1) {
        int v = s[t];
        if (t >= off) v += s[t - off];
        __syncthreads();
        s[t] = v;
        __syncthreads();
    }
    int run = (t == 0) ? 0 : s[t - 1];
    if (2 * t     < NBUCK) bstart[2 * t]     = run;
    if (2 * t + 1 < NBUCK) bstart[2 * t + 1] = run + a0;
    if (t == 0) bstart[NBUCK] = E;
}

__global__ __launch_bounds__(512) void scatter_kernel(
    const int* __restrict__ ei, int E,
    const int* __restrict__ bstart,
    const int* __restrict__ blkhist,
    int* __restrict__ packed,
    const int* __restrict__ flags)
{
    __shared__ int cur[NBUCK];
    int tid = threadIdx.x;
    long obase = (long)blockIdx.x * NBUCK;
    for (int i = tid; i < NBUCK; i += 512) cur[i] = bstart[i] + blkhist[obase + i];
    __syncthreads();
    int is64 = flags[1];
    long e0 = (long)blockIdx.x * SCHUNK;
    long e1 = e0 + SCHUNK; if (e1 > E) e1 = E;
    for (long j = e0 + tid; j < e1; j += 512) {
        int s = ldidx(ei, j, is64);
        int d = ldidx(ei, (long)E + j, is64);
        int b = d >> BSHIFT;
        int pos = atomicAdd(&cur[b], 1);
        packed[pos] = (s << BSHIFT) | (d & ((1 << BSHIFT) - 1));
    }
}

__global__ __launch_bounds__(256) void finefill_kernel(
    const int* __restrict__ bstart,
    const int* __restrict__ packed,
    int* __restrict__ rowptr,
    int* __restrict__ cnt,
    int* __restrict__ srclist)
{
    __shared__ int lcnt[1 << BSHIFT];
    __shared__ int lsum[256];
    int b = blockIdx.x;
    int tid = threadIdx.x;
    int nbase = b << BSHIFT;
    int beg = bstart[b];
    int end = bstart[b + 1];

    for (int i = tid; i < (1 << BSHIFT); i += 256) lcnt[i] = 0;
    __syncthreads();

    for (int j = beg + tid; j < end; j += 256)
        atomicAdd(&lcnt[packed[j] & ((1 << BSHIFT) - 1)], 1);
    __syncthreads();

    int i0 = tid * 4;
    int c0 = lcnt[i0], c1 = lcnt[i0 + 1], c2 = lcnt[i0 + 2], c3 = lcnt[i0 + 3];
    lsum[tid] = c0 + c1 + c2 + c3;
    __syncthreads();
    for (int off = 1; off < 256; off <<= 1) {
        int v = lsum[tid];
        if (tid >= off) v += lsum[tid - off];
        __syncthreads();
        lsum[tid] = v;
        __syncthreads();
    }
    int run = beg + ((tid == 0) ? 0 : lsum[tid - 1]);
    int r0 = run, r1 = r0 + c0, r2 = r1 + c1, r3 = r2 + c2;

    int n0 = nbase + i0;
    if (n0     < NT) { rowptr[n0]     = r0; cnt[n0]     = c0; }
    if (n0 + 1 < NT) { rowptr[n0 + 1] = r1; cnt[n0 + 1] = c1; }
    if (n0 + 2 < NT) { rowptr[n0 + 2] = r2; cnt[n0 + 2] = c2; }
    if (n0 + 3 < NT) { rowptr[n0 + 3] = r3; cnt[n0 + 3] = c3; }

    lcnt[i0] = r0; lcnt[i0 + 1] = r1; lcnt[i0 + 2] = r2; lcnt[i0 + 3] = r3;
    __syncthreads();

    for (int j = beg + tid; j < end; j += 256) {
        int p = packed[j];
        int dl = p & ((1 << BSHIFT) - 1);
        int pos = atomicAdd(&lcnt[dl], 1);
        srclist[pos] = p >> BSHIFT;
    }
}

// ---------------- fused SAGE layer v3: xout = act( mean @ Wl.T + b + xin @ Wr.T )
// 512 threads = 8 waves per 64-node tile. LDS holds ONLY the mean-exchange
// buffer (9.2KB vs 28KB) -> higher residency; weights read per-lane from the
// pre-converted global buffers (16KB, L1-hot) after the barrier. Gather loads
// predicated on q<cq (group-uniform -> shfl-safe) to cut wasted requests.
// User rows for layer 1 come directly from user_emb in bf16 mode (ub select).
template <bool RELU>
__global__ __launch_bounds__(512, 8) void sage_layer(
    const unsigned short* __restrict__ xin,
    const void* __restrict__ uemb,       // raw user_emb; used when use_uemb && isbf
    int use_uemb,
    const int* __restrict__ rowptr,
    const int* __restrict__ cnt,
    const int* __restrict__ srclist,
    const unsigned short* __restrict__ wWl,   // bf16 64x64 (pre-converted)
    const float* __restrict__ wb,             // f32 bias[64]
    const unsigned short* __restrict__ wWr,
    unsigned short* __restrict__ xout,
    const int* __restrict__ flags)
{
    __shared__ short8 lm8[HD * PD8];    // 9216 B, only LDS in this kernel

    int tid = threadIdx.x;
    int isbf = flags[0];
    const unsigned short* ub = (use_uemb && isbf) ? (const unsigned short*)uemb : xin;

    int tile = blockIdx.x;              // 64 nodes per tile; NT = 64*4375 exactly
    long base = (long)tile * HD * HD;

    int w8 = tid >> 6;                  // wave 0..7
    int lane = tid & 63;
    int mrow = lane & 15;
    int quad = lane >> 4;
    int roww = (w8 & 3) * 16 + mrow;    // combine row this lane serves
    int htp  = w8 >> 2;                 // h-tile pair selector (0 or 1)

    // ---- gather phase: 8 lanes per node, 8 nodes per wave
    int g = lane >> 3;                  // node group 0..7
    int sub = lane & 7;                 // 16B fragment 0..7 of the 128B row
    int nl = w8 * 8 + g;                // node local id 0..63
    int n = tile * 64 + nl;
    int beg = rowptr[n];
    int deg = cnt[n];

    float acc[8];
    #pragma unroll
    for (int k = 0; k < 8; ++k) acc[k] = 0.f;

    for (int j0 = 0; j0 < deg; j0 += 8) {
        int e = j0 + sub;
        int sv = (e < deg) ? srclist[beg + e] : 0;    // 8 coalesced ids per group
        int cq = deg - j0; if (cq > 8) cq = 8;        // group-uniform
        short8 r[8];
        #pragma unroll
        for (int q = 0; q < 8; ++q) {                 // predicated: no wasted requests
            if (q < cq) {
                int s = __shfl(sv, (g << 3) | q);     // source lane in-group & active
                const unsigned short* bp = (s < NU) ? ub : xin;
                r[q] = *(const short8*)&bp[(long)s * HD + sub * 8];
            }
        }
        #pragma unroll
        for (int q = 0; q < 8; ++q) {
            if (q < cq) {
                #pragma unroll
                for (int k = 0; k < 8; ++k)
                    acc[k] += bfu2f((unsigned short)r[q][k]);
            }
        }
    }

    float rd = 1.0f / fmaxf((float)deg, 1.0f);
    short8 o;
    #pragma unroll
    for (int k = 0; k < 8; ++k) o[k] = (short)f2bf_raw(acc[k] * rd);   // same rounding as before
    lm8[nl * PD8 + sub] = o;

    __syncthreads();   // means ready

    // ---- own-row A-fragments (post-barrier keeps gather-phase VGPR low)
    int gn = tile * 64 + roww;
    const unsigned short* bx = (gn < NU) ? ub : xin;
    const short8* xr = (const short8*)&bx[(long)gn * HD];
    short8 ax0 = xr[quad];
    short8 ax1 = xr[quad + 4];

    short8 am0 = lm8[roww * PD8 + quad];
    short8 am1 = lm8[roww * PD8 + 4 + quad];

    #pragma unroll
    for (int t = 0; t < 2; ++t) {
        int h = (htp * 2 + t) * 16 + mrow;
        const short8* pl = (const short8*)&wWl[h * HD];
        const short8* pr = (const short8*)&wWr[h * HD];
        short8 bl0 = pl[quad];
        short8 bl1 = pl[quad + 4];
        short8 br0 = pr[quad];
        short8 br1 = pr[quad + 4];
        floatx4 a = {0.f, 0.f, 0.f, 0.f};
        a = __builtin_amdgcn_mfma_f32_16x16x32_bf16(am0, bl0, a, 0, 0, 0);
        a = __builtin_amdgcn_mfma_f32_16x16x32_bf16(am1, bl1, a, 0, 0, 0);
        a = __builtin_amdgcn_mfma_f32_16x16x32_bf16(ax0, br0, a, 0, 0, 0);
        a = __builtin_amdgcn_mfma_f32_16x16x32_bf16(ax1, br1, a, 0, 0, 0);
        float bv = wb[h];
        #pragma unroll
        for (int r = 0; r < 4; ++r) {
            int node = (w8 & 3) * 16 + quad * 4 + r;
            float v = a[r] + bv;
            if (RELU) v = fmaxf(v, 0.0f);
            xout[base + node * HD + h] = f2bf_raw(v);
        }
    }
}

// ---------------- final: out[e] = dot(x2[u[e]], x2[NU + m[e]])
// v2: 2 lanes per edge (32-dim halves), 32 edges per wave; 8 independent 16B
// loads in flight per lane (2x MLP vs v1); single xor reduce.
__global__ __launch_bounds__(256) void dot_kernel(
    const unsigned short* __restrict__ x2,
    const int* __restrict__ eli,
    void* __restrict__ out,
    int EL,
    const int* __restrict__ flags)
{
    int wid = (blockIdx.x * 256 + threadIdx.x) >> 6;    // global wave id
    long base = (long)wid * 32;                          // first edge of this wave
    if (base >= EL) return;
    int lane = threadIdx.x & 63;
    int isbf = flags[0];
    int is64 = flags[1];

    // lanes 0..31 load u indices, lanes 32..63 load m indices
    int idxv = 0;
    long off = base + (lane & 31);
    if (off < EL) idxv = (lane < 32) ? ldidx(eli, off, is64)
                                     : ldidx(eli, (long)EL + off, is64);

    int eidx = lane >> 1;         // edge slot 0..31
    int half = lane & 1;          // 32-dim half of the row
    int u = __shfl(idxv, eidx);
    int m = __shfl(idxv, 32 + eidx);
    bool valid = (base + eidx) < EL;

    const short8* up = (const short8*)(x2 + (long)u * HD + half * 32);
    const short8* mp = (const short8*)(x2 + (long)(NU + m) * HD + half * 32);
    short8 a0 = up[0], a1 = up[1], a2 = up[2], a3 = up[3];
    short8 b0 = mp[0], b1 = mp[1], b2 = mp[2], b3 = mp[3];

    float p = 0.f;
    #pragma unroll
    for (int j = 0; j < 8; ++j) {
        p += bfu2f((unsigned short)a0[j]) * bfu2f((unsigned short)b0[j]);
        p += bfu2f((unsigned short)a1[j]) * bfu2f((unsigned short)b1[j]);
        p += bfu2f((unsigned short)a2[j]) * bfu2f((unsigned short)b2[j]);
        p += bfu2f((unsigned short)a3[j]) * bfu2f((unsigned short)b3[j]);
    }
    p += __shfl_xor(p, 1);

    if (half == 0 && valid) {
        long gidx = base + eidx;
        if (isbf) ((unsigned short*)out)[gidx] = f2bf_raw(p);
        else      ((float*)out)[gidx] = p;
    }
}

extern "C" void kernel_launch(void* const* d_in, const int* in_sizes, int n_in,
                              void* d_out, int out_size, void* d_ws, size_t ws_size,
                              hipStream_t stream)
{
    const void* movie_x   = d_in[0];
    const void* user_emb  = d_in[1];
    const void* movie_emb = d_in[2];
    const void* lin_W     = d_in[3];
    const void* lin_b     = d_in[4];
    const void* W1l       = d_in[5];
    const void* b1        = d_in[6];
    const void* W1r       = d_in[7];
    const void* W2l       = d_in[8];
    const void* b2        = d_in[9];
    const void* W2r       = d_in[10];
    const int* ei  = (const int*)d_in[11];
    const int* eli = (const int*)d_in[12];
    int E  = in_sizes[11] / 2;
    int EL = in_sizes[12] / 2;

    const int NSB = (E + SCHUNK - 1) / SCHUNK;          // hist/scatter blocks (306)

    char* w = (char*)d_ws;
    unsigned short* xb0     = (unsigned short*)w;  w += (size_t)NT * HD * 2;  // 35.84 MB
    unsigned short* xb1     = (unsigned short*)w;  w += (size_t)NT * HD * 2;  // 35.84 MB (ping-pong)
    int*            cnt     = (int*)w;             w += (size_t)NT * 4;
    int*            rowptr  = (int*)w;             w += (size_t)NT * 4;
    int*            srclist = (int*)w;             w += (size_t)E * 4;        // 5 MB
    int*            packed  = (int*)w;             w += (size_t)E * 4;        // 5 MB
    int*            bcnt    = (int*)w;             w += (size_t)(NBUCK + 1) * 4;
    int*            bstart  = (int*)w;             w += (size_t)(NBUCK + 1) * 4;
    int*            blkhist = (int*)w;             w += (size_t)NSB * NBUCK * 4;  // ~335 KB
    unsigned short* wsW     = (unsigned short*)w;  w += (size_t)4 * HD * HD * 2;  // 32 KB
    float*          wsb     = (float*)w;           w += (size_t)2 * HD * 4;
    int*            flags   = (int*)w;

    const int user_blocks   = (NU * HD / 8) / 256;      // 6250 exactly
    const int movie_blocks  = NM / 16;                  // 5000: 4 waves/block x 4 movies/wave
    const int tile_blocks   = NT / 64;                  // 4375 (512-thread blocks)
    const int dot_blocks    = ((EL + 31) / 32 + 3) / 4; // 3907

    probe_kernel<<<1, 64, 0, stream>>>(user_emb, ei, flags);
    prep_weights<<<1, 512, 0, stream>>>(W1l, b1, W1r, W2l, b2, W2r, wsW, wsb, flags);

    prep_user<<<user_blocks, 256, 0, stream>>>(user_emb, xb0, flags);
    prep_movie<<<movie_blocks, 256, 0, stream>>>(movie_x, movie_emb, lin_W, lin_b, xb0, flags);

    // CSR build (once; reused by both layers) -- fully atomic-free global path
    blk_hist<<<NSB, 512, 0, stream>>>(ei, E, blkhist, flags);
    col_scan<<<NBUCK, 256, 0, stream>>>(blkhist, NSB, bcnt);
    bucket_scan<<<1, 256, 0, stream>>>(bcnt, bstart, E);
    scatter_kernel<<<NSB, 512, 0, stream>>>(ei, E, bstart, blkhist, packed, flags);
    finefill_kernel<<<NBUCK, 256, 0, stream>>>(bstart, packed, rowptr, cnt, srclist);

    // fused layers (ping-pong xb0 -> xb1 -> xb0); layer 1 reads users from user_emb in bf16 mode
    sage_layer<true><<<tile_blocks, 512, 0, stream>>>(
        xb0, user_emb, 1, rowptr, cnt, srclist, wsW, wsb, wsW + HD * HD, xb1, flags);
    sage_layer<false><<<tile_blocks, 512, 0, stream>>>(
        xb1, user_emb, 0, rowptr, cnt, srclist, wsW + 2 * HD * HD, wsb + HD, wsW + 3 * HD * HD, xb0, flags);

    // final edge dot products
    dot_kernel<<<dot_blocks, 256, 0, stream>>>(xb0, eli, d_out, EL, flags);
}

// Round 8
// 350.886 us; speedup vs baseline: 1.0677x; 1.0677x over previous
//
#include <hip/hip_runtime.h>
#include <hip/hip_bf16.h>

#define NU 200000
#define NM 80000
#define NT 280000   // NU + NM
#define HD 64
#define FM 20

#define BSHIFT 10
#define NBUCK ((NT + 1023) >> 10)   // 274 buckets of 1024 nodes
#define SCHUNK 4096                 // edges per hist/scatter block

#define PD8 9        // padded LDS row: 9 x short8 slots (144B, odd -> conflict-free)

typedef __attribute__((ext_vector_type(8))) short short8;
typedef __attribute__((ext_vector_type(4))) float floatx4;

__device__ __forceinline__ float bfu2f(unsigned short u) {
    union { unsigned int u; float f; } c; c.u = ((unsigned int)u) << 16; return c.f;
}

__device__ __forceinline__ unsigned short f2bf_raw(float f) {
    union { float f; unsigned int u; } c; c.f = f;
    unsigned int u = c.u + 0x7FFFu + ((c.u >> 16) & 1u);   // round-nearest-even
    return (unsigned short)(u >> 16);
}

__device__ __forceinline__ float ldf(const void* p, long i, int isbf) {
    return isbf ? bfu2f(((const unsigned short*)p)[i]) : ((const float*)p)[i];
}
__device__ __forceinline__ int ldidx(const int* p, long j, int is64) {
    return is64 ? p[2 * j] : p[j];
}

// ---------------- probe + weight prep fused (one block).
// Wave 0 probes dtypes -> flags; then all 512 threads convert the 4 SAGE weight
// matrices to bf16 (+ f32 biases) into workspace. sage_layer reads them straight
// from global (16KB, L1-hot) instead of LDS staging.
__global__ __launch_bounds__(512) void probe_prep(
    const void* __restrict__ user_emb, const int* __restrict__ ei,
    const void* __restrict__ W1l, const void* __restrict__ b1, const void* __restrict__ W1r,
    const void* __restrict__ W2l, const void* __restrict__ b2, const void* __restrict__ W2r,
    unsigned short* __restrict__ wsW,   // 4 x 4096 shorts: W1l, W1r, W2l, W2r
    float* __restrict__ wsb,            // 2 x 64 floats: b1, b2
    int* __restrict__ flags)
{
    __shared__ int lfl[2];
    int t = threadIdx.x;
    if (t < 64) {
        int bad = 0;
        for (int i = t; i < 128; i += 64) {
            unsigned short h = ((const unsigned short*)user_emb)[i];
            unsigned int e = (h >> 7) & 0xFF;
            if (e >= 135) bad = 1;           // |x| >= 256, or Inf/NaN -> not real bf16
        }
        unsigned long long mf = __ballot(bad != 0);
        int odd_nonzero = 0;
        if (t < 16 && ei[2 * t + 1] != 0) odd_nonzero = 1;
        unsigned long long mi = __ballot(odd_nonzero != 0);
        if (t == 0) {
            lfl[0] = (mf == 0) ? 1 : 0;
            lfl[1] = (mi == 0) ? 1 : 0;
            flags[0] = lfl[0];
            flags[1] = lfl[1];
        }
    }
    __syncthreads();
    int isbf = lfl[0];

    const void* srcs[4] = {W1l, W1r, W2l, W2r};
    #pragma unroll
    for (int w = 0; w < 4; ++w) {
        unsigned short* dst = wsW + w * (HD * HD);
        if (isbf) {
            ((short8*)dst)[t] = ((const short8*)srcs[w])[t];   // 512 x short8 = 4096 exactly
        } else {
            floatx4 a = ((const floatx4*)srcs[w])[2 * t];
            floatx4 b = ((const floatx4*)srcs[w])[2 * t + 1];
            short8 r;
            r[0]=(short)f2bf_raw(a[0]); r[1]=(short)f2bf_raw(a[1]); r[2]=(short)f2bf_raw(a[2]); r[3]=(short)f2bf_raw(a[3]);
            r[4]=(short)f2bf_raw(b[0]); r[5]=(short)f2bf_raw(b[1]); r[6]=(short)f2bf_raw(b[2]); r[7]=(short)f2bf_raw(b[3]);
            ((short8*)dst)[t] = r;
        }
    }
    if (t < HD) {
        wsb[t]      = ldf(b1, t, isbf);
        wsb[HD + t] = ldf(b2, t, isbf);
    }
}

// ---------------- prep A: user rows. bf16 mode: UNUSED (sage layer 1 reads
// user_emb directly) -> early-exit. fp32 mode converts as before.
__global__ __launch_bounds__(256) void prep_user(
    const void* __restrict__ user_emb,
    unsigned short* __restrict__ xb,
    const int* __restrict__ flags)
{
    if (flags[0]) return;               // bf16: no copy needed
    long t = (long)blockIdx.x * 256 + threadIdx.x;        // t < NU*HD/8 = 1.6M exactly
    floatx4 a = ((const floatx4*)user_emb)[2 * t];
    floatx4 b = ((const floatx4*)user_emb)[2 * t + 1];
    short8 r;
    r[0] = (short)f2bf_raw(a[0]); r[1] = (short)f2bf_raw(a[1]);
    r[2] = (short)f2bf_raw(a[2]); r[3] = (short)f2bf_raw(a[3]);
    r[4] = (short)f2bf_raw(b[0]); r[5] = (short)f2bf_raw(b[1]);
    r[6] = (short)f2bf_raw(b[2]); r[7] = (short)f2bf_raw(b[3]);
    ((short8*)xb)[t] = r;
}

// ---------------- prep B: movie rows, latency-optimized (unchanged).
__global__ __launch_bounds__(256) void prep_movie(
    const void* __restrict__ movie_x,
    const void* __restrict__ movie_emb,
    const void* __restrict__ lin_W,
    const void* __restrict__ lin_b,
    unsigned short* __restrict__ xb,
    const int* __restrict__ flags)
{
    int isbf = flags[0];
    int tid = threadIdx.x;
    int lane = tid & 63;
    int wave = blockIdx.x * 4 + (tid >> 6);
    int m0 = __builtin_amdgcn_readfirstlane(wave << 2);   // 4 movies per wave
    if (m0 >= NM) return;

    float wr[FM];
    if (isbf) {
        const unsigned int* p = (const unsigned int*)((const unsigned short*)lin_W + (long)lane * FM);
        #pragma unroll
        for (int i = 0; i < FM / 2; ++i) {
            unsigned int u = p[i];
            wr[2 * i]     = bfu2f((unsigned short)(u & 0xFFFFu));
            wr[2 * i + 1] = bfu2f((unsigned short)(u >> 16));
        }
    } else {
        const floatx4* p = (const floatx4*)((const float*)lin_W + (long)lane * FM);
        #pragma unroll
        for (int i = 0; i < FM / 4; ++i) {
            floatx4 v = p[i];
            wr[4 * i] = v[0]; wr[4 * i + 1] = v[1]; wr[4 * i + 2] = v[2]; wr[4 * i + 3] = v[3];
        }
    }
    float bias = ldf(lin_b, lane, isbf);

    #pragma unroll
    for (int mm = 0; mm < 4; ++mm) {
        int m = m0 + mm;
        float a0 = bias + ldf(movie_emb, (long)m * HD + lane, isbf);
        float a1 = 0.f, a2 = 0.f, a3 = 0.f;
        if (isbf) {
            const unsigned int* mr = (const unsigned int*)((const unsigned short*)movie_x + (long)m * FM);
            #pragma unroll
            for (int kk = 0; kk < FM / 2; ++kk) {
                unsigned int u = mr[kk];
                float x0 = bfu2f((unsigned short)(u & 0xFFFFu));
                float x1 = bfu2f((unsigned short)(u >> 16));
                if (kk & 1) { a2 += x0 * wr[2 * kk]; a3 += x1 * wr[2 * kk + 1]; }
                else        { a0 += x0 * wr[2 * kk]; a1 += x1 * wr[2 * kk + 1]; }
            }
        } else {
            const float* mr = (const float*)movie_x + (long)m * FM;
            #pragma unroll
            for (int k = 0; k < FM; k += 4) {
                a0 += mr[k]     * wr[k];
                a1 += mr[k + 1] * wr[k + 1];
                a2 += mr[k + 2] * wr[k + 2];
                a3 += mr[k + 3] * wr[k + 3];
            }
        }
        xb[(long)(NU + m) * HD + lane] = f2bf_raw((a0 + a1) + (a2 + a3));
    }
}

// ---------------- CSR build: atomic-free scatter via 2D histogram scan ----
__global__ __launch_bounds__(512) void blk_hist(
    const int* __restrict__ ei, int E,
    int* __restrict__ blkhist,
    const int* __restrict__ flags)
{
    __shared__ int h[NBUCK];
    int tid = threadIdx.x;
    for (int i = tid; i < NBUCK; i += 512) h[i] = 0;
    __syncthreads();
    int is64 = flags[1];
    long e0 = (long)blockIdx.x * SCHUNK;
    long e1 = e0 + SCHUNK; if (e1 > E) e1 = E;
    for (long j = e0 + tid; j < e1; j += 512) {
        int d = ldidx(ei, (long)E + j, is64);
        atomicAdd(&h[d >> BSHIFT], 1);
    }
    __syncthreads();
    long obase = (long)blockIdx.x * NBUCK;
    for (int i = tid; i < NBUCK; i += 512) blkhist[obase + i] = h[i];
}

__global__ __launch_bounds__(256) void col_scan(
    int* __restrict__ blkhist, int NSB,
    int* __restrict__ bcnt)
{
    __shared__ int larr[2048];
    __shared__ int lsum[256];
    int b = blockIdx.x;
    int t = threadIdx.x;
    for (int i = t; i < NSB; i += 256) larr[i] = blkhist[(long)i * NBUCK + b];
    __syncthreads();
    int C = (NSB + 255) >> 8;
    int beg = t * C;
    int end = beg + C; if (end > NSB) end = NSB; if (beg > NSB) beg = NSB;
    int s = 0;
    for (int i = beg; i < end; ++i) s += larr[i];
    lsum[t] = s;
    __syncthreads();
    for (int off = 1; off < 256; off <<= 1) {
        int v = lsum[t];
        if (t >= off) v += lsum[t - off];
        __syncthreads();
        lsum[t] = v;
        __syncthreads();
    }
    int run = (t == 0) ? 0 : lsum[t - 1];
    for (int i = beg; i < end; ++i) {
        int v = larr[i];
        blkhist[(long)i * NBUCK + b] = run;   // exclusive offset of block i in bucket b
        run += v;
    }
    if (t == 0) bcnt[b] = lsum[255];
}

__global__ __launch_bounds__(256) void bucket_scan(
    const int* __restrict__ bcnt, int* __restrict__ bstart, int E)
{
    __shared__ int s[256];
    int t = threadIdx.x;
    int a0 = (2 * t     < NBUCK) ? bcnt[2 * t]     : 0;
    int a1 = (2 * t + 1 < NBUCK) ? bcnt[2 * t + 1] : 0;
    s[t] = a0 + a1;
    __syncthreads();
    for (int off = 1; off < 256; off <<= 1) {
        int v = s[t];
        if (t >= off) v += s[t - off];
        __syncthreads();
        s[t] = v;
        __syncthreads();
    }
    int run = (t == 0) ? 0 : s[t - 1];
    if (2 * t     < NBUCK) bstart[2 * t]     = run;
    if (2 * t + 1 < NBUCK) bstart[2 * t + 1] = run + a0;
    if (t == 0) bstart[NBUCK] = E;
}

__global__ __launch_bounds__(512) void scatter_kernel(
    const int* __restrict__ ei, int E,
    const int* __restrict__ bstart,
    const int* __restrict__ blkhist,
    int* __restrict__ packed,
    const int* __restrict__ flags)
{
    __shared__ int cur[NBUCK];
    int tid = threadIdx.x;
    long obase = (long)blockIdx.x * NBUCK;
    for (int i = tid; i < NBUCK; i += 512) cur[i] = bstart[i] + blkhist[obase + i];
    __syncthreads();
    int is64 = flags[1];
    long e0 = (long)blockIdx.x * SCHUNK;
    long e1 = e0 + SCHUNK; if (e1 > E) e1 = E;
    for (long j = e0 + tid; j < e1; j += 512) {
        int s = ldidx(ei, j, is64);
        int d = ldidx(ei, (long)E + j, is64);
        int b = d >> BSHIFT;
        int pos = atomicAdd(&cur[b], 1);
        packed[pos] = (s << BSHIFT) | (d & ((1 << BSHIFT) - 1));
    }
}

__global__ __launch_bounds__(256) void finefill_kernel(
    const int* __restrict__ bstart,
    const int* __restrict__ packed,
    int* __restrict__ rowptr,
    int* __restrict__ cnt,
    int* __restrict__ srclist)
{
    __shared__ int lcnt[1 << BSHIFT];
    __shared__ int lsum[256];
    int b = blockIdx.x;
    int tid = threadIdx.x;
    int nbase = b << BSHIFT;
    int beg = bstart[b];
    int end = bstart[b + 1];

    for (int i = tid; i < (1 << BSHIFT); i += 256) lcnt[i] = 0;
    __syncthreads();

    for (int j = beg + tid; j < end; j += 256)
        atomicAdd(&lcnt[packed[j] & ((1 << BSHIFT) - 1)], 1);
    __syncthreads();

    int i0 = tid * 4;
    int c0 = lcnt[i0], c1 = lcnt[i0 + 1], c2 = lcnt[i0 + 2], c3 = lcnt[i0 + 3];
    lsum[tid] = c0 + c1 + c2 + c3;
    __syncthreads();
    for (int off = 1; off < 256; off <<= 1) {
        int v = lsum[tid];
        if (tid >= off) v += lsum[tid - off];
        __syncthreads();
        lsum[tid] = v;
        __syncthreads();
    }
    int run = beg + ((tid == 0) ? 0 : lsum[tid - 1]);
    int r0 = run, r1 = r0 + c0, r2 = r1 + c1, r3 = r2 + c2;

    int n0 = nbase + i0;
    if (n0     < NT) { rowptr[n0]     = r0; cnt[n0]     = c0; }
    if (n0 + 1 < NT) { rowptr[n0 + 1] = r1; cnt[n0 + 1] = c1; }
    if (n0 + 2 < NT) { rowptr[n0 + 2] = r2; cnt[n0 + 2] = c2; }
    if (n0 + 3 < NT) { rowptr[n0 + 3] = r3; cnt[n0 + 3] = c3; }

    lcnt[i0] = r0; lcnt[i0 + 1] = r1; lcnt[i0 + 2] = r2; lcnt[i0 + 3] = r3;
    __syncthreads();

    for (int j = beg + tid; j < end; j += 256) {
        int p = packed[j];
        int dl = p & ((1 << BSHIFT) - 1);
        int pos = atomicAdd(&lcnt[dl], 1);
        srclist[pos] = p >> BSHIFT;
    }
}

// ---------------- fused SAGE layer v4: xout = act( mean @ Wl.T + b + xin @ Wr.T )
// R5's proven gather pipeline (8 UNPREDICATED 16B loads in flight per lane; the
// compiler must NOT be VGPR-capped -> no min-wave launch bound) + 9.2KB LDS
// (means only) + weights from pre-converted global (L1-hot). UEMB template:
// layer 1 in bf16 reads user rows straight from user_emb (no prep copy).
template <bool RELU, bool UEMB>
__global__ __launch_bounds__(512) void sage_layer(
    const unsigned short* __restrict__ xin,
    const void* __restrict__ uemb,
    const int* __restrict__ rowptr,
    const int* __restrict__ cnt,
    const int* __restrict__ srclist,
    const unsigned short* __restrict__ wWl,   // bf16 64x64 (pre-converted)
    const float* __restrict__ wb,             // f32 bias[64]
    const unsigned short* __restrict__ wWr,
    unsigned short* __restrict__ xout,
    const int* __restrict__ flags)
{
    __shared__ short8 lm8[HD * PD8];    // 9216 B, only LDS in this kernel

    int tid = threadIdx.x;
    int isbf = flags[0];
    const unsigned short* ub = (UEMB && isbf) ? (const unsigned short*)uemb : xin;

    int tile = blockIdx.x;              // 64 nodes per tile; NT = 64*4375 exactly
    long base = (long)tile * HD * HD;

    int w8 = tid >> 6;                  // wave 0..7
    int lane = tid & 63;
    int mrow = lane & 15;
    int quad = lane >> 4;
    int roww = (w8 & 3) * 16 + mrow;    // combine row this lane serves
    int htp  = w8 >> 2;                 // h-tile pair selector (0 or 1)

    // ---- gather phase: 8 lanes per node, 8 nodes per wave
    int g = lane >> 3;                  // node group 0..7
    int sub = lane & 7;                 // 16B fragment 0..7 of the 128B row
    int nl = w8 * 8 + g;                // node local id 0..63
    int n = tile * 64 + nl;
    int beg = rowptr[n];
    int deg = cnt[n];

    float acc[8];
    #pragma unroll
    for (int k = 0; k < 8; ++k) acc[k] = 0.f;

    for (int j0 = 0; j0 < deg; j0 += 8) {
        int e = j0 + sub;
        int sv = (e < deg) ? srclist[beg + e] : 0;    // 8 coalesced ids per group
        int cq = deg - j0; if (cq > 8) cq = 8;
        short8 r[8];
        #pragma unroll
        for (int q = 0; q < 8; ++q) {                 // 8 independent loads in flight
            int s = __shfl(sv, (g << 3) | q);
            if (UEMB) {
                const unsigned short* bp = (s < NU) ? ub : xin;
                r[q] = *(const short8*)&bp[(long)s * HD + sub * 8];
            } else {
                r[q] = *(const short8*)&xin[(long)s * HD + sub * 8];
            }
        }
        #pragma unroll
        for (int q = 0; q < 8; ++q) {
            if (q < cq) {
                #pragma unroll
                for (int k = 0; k < 8; ++k)
                    acc[k] += bfu2f((unsigned short)r[q][k]);
            }
        }
    }

    float rd = 1.0f / fmaxf((float)deg, 1.0f);
    short8 o;
    #pragma unroll
    for (int k = 0; k < 8; ++k) o[k] = (short)f2bf_raw(acc[k] * rd);   // same rounding as before
    lm8[nl * PD8 + sub] = o;

    // own-row A-fragments: issue BEFORE the barrier so latency overlaps the wait
    int gn = tile * 64 + roww;
    const unsigned short* bx = (UEMB && (gn < NU)) ? ub : xin;
    const short8* xr = (const short8*)&bx[(long)gn * HD];
    short8 ax0 = xr[quad];
    short8 ax1 = xr[quad + 4];

    __syncthreads();   // means ready

    short8 am0 = lm8[roww * PD8 + quad];
    short8 am1 = lm8[roww * PD8 + 4 + quad];

    #pragma unroll
    for (int t = 0; t < 2; ++t) {
        int h = (htp * 2 + t) * 16 + mrow;
        const short8* pl = (const short8*)&wWl[h * HD];
        const short8* pr = (const short8*)&wWr[h * HD];
        short8 bl0 = pl[quad];
        short8 bl1 = pl[quad + 4];
        short8 br0 = pr[quad];
        short8 br1 = pr[quad + 4];
        floatx4 a = {0.f, 0.f, 0.f, 0.f};
        a = __builtin_amdgcn_mfma_f32_16x16x32_bf16(am0, bl0, a, 0, 0, 0);
        a = __builtin_amdgcn_mfma_f32_16x16x32_bf16(am1, bl1, a, 0, 0, 0);
        a = __builtin_amdgcn_mfma_f32_16x16x32_bf16(ax0, br0, a, 0, 0, 0);
        a = __builtin_amdgcn_mfma_f32_16x16x32_bf16(ax1, br1, a, 0, 0, 0);
        float bv = wb[h];
        #pragma unroll
        for (int r = 0; r < 4; ++r) {
            int node = (w8 & 3) * 16 + quad * 4 + r;
            float v = a[r] + bv;
            if (RELU) v = fmaxf(v, 0.0f);
            xout[base + node * HD + h] = f2bf_raw(v);
        }
    }
}

// ---------------- final: out[e] = dot(x2[u[e]], x2[NU + m[e]])
// 4 lanes per edge, 16 edges per wave (R5-proven version).
__global__ __launch_bounds__(256) void dot_kernel(
    const unsigned short* __restrict__ x2,
    const int* __restrict__ eli,
    void* __restrict__ out,
    int EL,
    const int* __restrict__ flags)
{
    int wid = (blockIdx.x * 256 + threadIdx.x) >> 6;    // global wave id
    long base = (long)wid * 16;                          // first edge of this wave
    if (base >= EL) return;
    int lane = threadIdx.x & 63;
    int isbf = flags[0];
    int is64 = flags[1];

    int idxv = 0;
    if (lane < 16)      idxv = ldidx(eli, base + lane, is64);
    else if (lane < 32) idxv = ldidx(eli, (long)EL + base + (lane - 16), is64);

    int e   = lane >> 2;          // edge slot 0..15
    int seg = lane & 3;           // 16-element segment of the 64-dim row
    int u = __shfl(idxv, e);
    int m = __shfl(idxv, 16 + e);

    const short8* up = (const short8*)(x2 + (long)u * HD + seg * 16);
    const short8* mp = (const short8*)(x2 + (long)(NU + m) * HD + seg * 16);
    short8 a0 = up[0], a1 = up[1];
    short8 b0 = mp[0], b1 = mp[1];

    float p = 0.f;
    #pragma unroll
    for (int j = 0; j < 8; ++j) {
        p += bfu2f((unsigned short)a0[j]) * bfu2f((unsigned short)b0[j]);
        p += bfu2f((unsigned short)a1[j]) * bfu2f((unsigned short)b1[j]);
    }
    p += __shfl_xor(p, 1);
    p += __shfl_xor(p, 2);

    if (seg == 0) {
        long g = base + e;
        if (isbf) ((unsigned short*)out)[g] = f2bf_raw(p);
        else      ((float*)out)[g] = p;
    }
}

extern "C" void kernel_launch(void* const* d_in, const int* in_sizes, int n_in,
                              void* d_out, int out_size, void* d_ws, size_t ws_size,
                              hipStream_t stream)
{
    const void* movie_x   = d_in[0];
    const void* user_emb  = d_in[1];
    const void* movie_emb = d_in[2];
    const void* lin_W     = d_in[3];
    const void* lin_b     = d_in[4];
    const void* W1l       = d_in[5];
    const void* b1        = d_in[6];
    const void* W1r       = d_in[7];
    const void* W2l       = d_in[8];
    const void* b2        = d_in[9];
    const void* W2r       = d_in[10];
    const int* ei  = (const int*)d_in[11];
    const int* eli = (const int*)d_in[12];
    int E  = in_sizes[11] / 2;
    int EL = in_sizes[12] / 2;

    const int NSB = (E + SCHUNK - 1) / SCHUNK;          // hist/scatter blocks (306)

    char* w = (char*)d_ws;
    unsigned short* xb0     = (unsigned short*)w;  w += (size_t)NT * HD * 2;  // 35.84 MB
    unsigned short* xb1     = (unsigned short*)w;  w += (size_t)NT * HD * 2;  // 35.84 MB (ping-pong)
    int*            cnt     = (int*)w;             w += (size_t)NT * 4;
    int*            rowptr  = (int*)w;             w += (size_t)NT * 4;
    int*            srclist = (int*)w;             w += (size_t)E * 4;        // 5 MB
    int*            packed  = (int*)w;             w += (size_t)E * 4;        // 5 MB
    int*            bcnt    = (int*)w;             w += (size_t)(NBUCK + 1) * 4;
    int*            bstart  = (int*)w;             w += (size_t)(NBUCK + 1) * 4;
    int*            blkhist = (int*)w;             w += (size_t)NSB * NBUCK * 4;  // ~335 KB
    unsigned short* wsW     = (unsigned short*)w;  w += (size_t)4 * HD * HD * 2;  // 32 KB
    float*          wsb     = (float*)w;           w += (size_t)2 * HD * 4;
    int*            flags   = (int*)w;

    const int user_blocks   = (NU * HD / 8) / 256;      // 6250 exactly
    const int movie_blocks  = NM / 16;                  // 5000: 4 waves/block x 4 movies/wave
    const int tile_blocks   = NT / 64;                  // 4375 (512-thread blocks)
    const int dot_blocks    = ((EL + 15) / 16 + 3) / 4; // 7813

    probe_prep<<<1, 512, 0, stream>>>(user_emb, ei, W1l, b1, W1r, W2l, b2, W2r, wsW, wsb, flags);

    prep_user<<<user_blocks, 256, 0, stream>>>(user_emb, xb0, flags);
    prep_movie<<<movie_blocks, 256, 0, stream>>>(movie_x, movie_emb, lin_W, lin_b, xb0, flags);

    // CSR build (once; reused by both layers) -- fully atomic-free global path
    blk_hist<<<NSB, 512, 0, stream>>>(ei, E, blkhist, flags);
    col_scan<<<NBUCK, 256, 0, stream>>>(blkhist, NSB, bcnt);
    bucket_scan<<<1, 256, 0, stream>>>(bcnt, bstart, E);
    scatter_kernel<<<NSB, 512, 0, stream>>>(ei, E, bstart, blkhist, packed, flags);
    finefill_kernel<<<NBUCK, 256, 0, stream>>>(bstart, packed, rowptr, cnt, srclist);

    // fused layers (ping-pong xb0 -> xb1 -> xb0); layer 1 reads users from user_emb in bf16 mode
    sage_layer<true, true><<<tile_blocks, 512, 0, stream>>>(
        xb0, user_emb, rowptr, cnt, srclist, wsW, wsb, wsW + HD * HD, xb1, flags);
    sage_layer<false, false><<<tile_blocks, 512, 0, stream>>>(
        xb1, user_emb, rowptr, cnt, srclist, wsW + 2 * HD * HD, wsb + HD, wsW + 3 * HD * HD, xb0, flags);

    // final edge dot products
    dot_kernel<<<dot_blocks, 256, 0, stream>>>(xb0, eli, d_out, EL, flags);
}

// Round 9
// 304.111 us; speedup vs baseline: 1.2320x; 1.1538x over previous
//
#include <hip/hip_runtime.h>
#include <hip/hip_bf16.h>

#define NU 200000
#define NM 80000
#define NT 280000   // NU + NM
#define HD 64
#define FM 20

#define BSHIFT 10
#define NBUCK ((NT + 1023) >> 10)   // 274 buckets of 1024 nodes
#define SCHUNK 4096                 // edges per hist/scatter block

#define PD 72        // padded LDS row: 72 shorts = 144 B = 9 x 16B slots (odd -> conflict-free)
#define PD8 (PD / 8) // 9 short8 slots per row

typedef __attribute__((ext_vector_type(8))) short short8;
typedef __attribute__((ext_vector_type(4))) float floatx4;

__device__ __forceinline__ float bfu2f(unsigned short u) {
    union { unsigned int u; float f; } c; c.u = ((unsigned int)u) << 16; return c.f;
}

__device__ __forceinline__ unsigned short f2bf_raw(float f) {
    union { float f; unsigned int u; } c; c.f = f;
    unsigned int u = c.u + 0x7FFFu + ((c.u >> 16) & 1u);   // round-nearest-even
    return (unsigned short)(u >> 16);
}

__device__ __forceinline__ float ldf(const void* p, long i, int isbf) {
    return isbf ? bfu2f(((const unsigned short*)p)[i]) : ((const float*)p)[i];
}
__device__ __forceinline__ int ldidx(const int* p, long j, int is64) {
    return is64 ? p[2 * j] : p[j];
}

// ---------------- runtime dtype probe -> flags[0]=isbf16, flags[1]=isint64
__global__ void probe_kernel(const void* user_emb, const int* ei, int* flags) {
    int t = threadIdx.x;
    int bad = 0;
    for (int i = t; i < 128; i += 64) {
        unsigned short h = ((const unsigned short*)user_emb)[i];
        unsigned int e = (h >> 7) & 0xFF;
        if (e >= 135) bad = 1;               // |x| >= 256, or Inf/NaN -> not real bf16
    }
    unsigned long long mf = __ballot(bad != 0);
    int odd_nonzero = 0;
    if (t < 16 && ei[2 * t + 1] != 0) odd_nonzero = 1;
    unsigned long long mi = __ballot(odd_nonzero != 0);
    if (t == 0) {
        flags[0] = (mf == 0) ? 1 : 0;
        flags[1] = (mi == 0) ? 1 : 0;
    }
}

// ---------------- prep A: user rows, vectorized copy/convert (8 elems/thread)
__global__ __launch_bounds__(256) void prep_user(
    const void* __restrict__ user_emb,
    unsigned short* __restrict__ xb,
    const int* __restrict__ flags)
{
    long t = (long)blockIdx.x * 256 + threadIdx.x;        // t < NU*HD/8 = 1.6M exactly
    int isbf = flags[0];
    if (isbf) {
        ((short8*)xb)[t] = ((const short8*)user_emb)[t];
    } else {
        floatx4 a = ((const floatx4*)user_emb)[2 * t];
        floatx4 b = ((const floatx4*)user_emb)[2 * t + 1];
        short8 r;
        r[0] = (short)f2bf_raw(a[0]); r[1] = (short)f2bf_raw(a[1]);
        r[2] = (short)f2bf_raw(a[2]); r[3] = (short)f2bf_raw(a[3]);
        r[4] = (short)f2bf_raw(b[0]); r[5] = (short)f2bf_raw(b[1]);
        r[6] = (short)f2bf_raw(b[2]); r[7] = (short)f2bf_raw(b[3]);
        ((short8*)xb)[t] = r;
    }
}

// ---------------- prep B: movie rows, latency-optimized (unchanged).
__global__ __launch_bounds__(256) void prep_movie(
    const void* __restrict__ movie_x,
    const void* __restrict__ movie_emb,
    const void* __restrict__ lin_W,
    const void* __restrict__ lin_b,
    unsigned short* __restrict__ xb,
    const int* __restrict__ flags)
{
    int isbf = flags[0];
    int tid = threadIdx.x;
    int lane = tid & 63;
    int wave = blockIdx.x * 4 + (tid >> 6);
    int m0 = __builtin_amdgcn_readfirstlane(wave << 2);   // 4 movies per wave
    if (m0 >= NM) return;

    float wr[FM];
    if (isbf) {
        const unsigned int* p = (const unsigned int*)((const unsigned short*)lin_W + (long)lane * FM);
        #pragma unroll
        for (int i = 0; i < FM / 2; ++i) {
            unsigned int u = p[i];
            wr[2 * i]     = bfu2f((unsigned short)(u & 0xFFFFu));
            wr[2 * i + 1] = bfu2f((unsigned short)(u >> 16));
        }
    } else {
        const floatx4* p = (const floatx4*)((const float*)lin_W + (long)lane * FM);
        #pragma unroll
        for (int i = 0; i < FM / 4; ++i) {
            floatx4 v = p[i];
            wr[4 * i] = v[0]; wr[4 * i + 1] = v[1]; wr[4 * i + 2] = v[2]; wr[4 * i + 3] = v[3];
        }
    }
    float bias = ldf(lin_b, lane, isbf);

    #pragma unroll
    for (int mm = 0; mm < 4; ++mm) {
        int m = m0 + mm;
        float a0 = bias + ldf(movie_emb, (long)m * HD + lane, isbf);
        float a1 = 0.f, a2 = 0.f, a3 = 0.f;
        if (isbf) {
            const unsigned int* mr = (const unsigned int*)((const unsigned short*)movie_x + (long)m * FM);
            #pragma unroll
            for (int kk = 0; kk < FM / 2; ++kk) {
                unsigned int u = mr[kk];
                float x0 = bfu2f((unsigned short)(u & 0xFFFFu));
                float x1 = bfu2f((unsigned short)(u >> 16));
                if (kk & 1) { a2 += x0 * wr[2 * kk]; a3 += x1 * wr[2 * kk + 1]; }
                else        { a0 += x0 * wr[2 * kk]; a1 += x1 * wr[2 * kk + 1]; }
            }
        } else {
            const float* mr = (const float*)movie_x + (long)m * FM;
            #pragma unroll
            for (int k = 0; k < FM; k += 4) {
                a0 += mr[k]     * wr[k];
                a1 += mr[k + 1] * wr[k + 1];
                a2 += mr[k + 2] * wr[k + 2];
                a3 += mr[k + 3] * wr[k + 3];
            }
        }
        xb[(long)(NU + m) * HD + lane] = f2bf_raw((a0 + a1) + (a2 + a3));
    }
}

// ---------------- CSR build: atomic-free scatter via 2D histogram scan ----
__global__ __launch_bounds__(512) void blk_hist(
    const int* __restrict__ ei, int E,
    int* __restrict__ blkhist,
    const int* __restrict__ flags)
{
    __shared__ int h[NBUCK];
    int tid = threadIdx.x;
    for (int i = tid; i < NBUCK; i += 512) h[i] = 0;
    __syncthreads();
    int is64 = flags[1];
    long e0 = (long)blockIdx.x * SCHUNK;
    long e1 = e0 + SCHUNK; if (e1 > E) e1 = E;
    for (long j = e0 + tid; j < e1; j += 512) {
        int d = ldidx(ei, (long)E + j, is64);
        atomicAdd(&h[d >> BSHIFT], 1);
    }
    __syncthreads();
    long obase = (long)blockIdx.x * NBUCK;
    for (int i = tid; i < NBUCK; i += 512) blkhist[obase + i] = h[i];
}

__global__ __launch_bounds__(256) void col_scan(
    int* __restrict__ blkhist, int NSB,
    int* __restrict__ bcnt)
{
    __shared__ int larr[2048];
    __shared__ int lsum[256];
    int b = blockIdx.x;
    int t = threadIdx.x;
    for (int i = t; i < NSB; i += 256) larr[i] = blkhist[(long)i * NBUCK + b];
    __syncthreads();
    int C = (NSB + 255) >> 8;
    int beg = t * C;
    int end = beg + C; if (end > NSB) end = NSB; if (beg > NSB) beg = NSB;
    int s = 0;
    for (int i = beg; i < end; ++i) s += larr[i];
    lsum[t] = s;
    __syncthreads();
    for (int off = 1; off < 256; off <<= 1) {
        int v = lsum[t];
        if (t >= off) v += lsum[t - off];
        __syncthreads();
        lsum[t] = v;
        __syncthreads();
    }
    int run = (t == 0) ? 0 : lsum[t - 1];
    for (int i = beg; i < end; ++i) {
        int v = larr[i];
        blkhist[(long)i * NBUCK + b] = run;   // exclusive offset of block i in bucket b
        run += v;
    }
    if (t == 0) bcnt[b] = lsum[255];
}

__global__ __launch_bounds__(256) void bucket_scan(
    const int* __restrict__ bcnt, int* __restrict__ bstart, int E)
{
    __shared__ int s[256];
    int t = threadIdx.x;
    int a0 = (2 * t     < NBUCK) ? bcnt[2 * t]     : 0;
    int a1 = (2 * t + 1 < NBUCK) ? bcnt[2 * t + 1] : 0;
    s[t] = a0 + a1;
    __syncthreads();
    for (int off = 1; off < 256; off <<= 1) {
        int v = s[t];
        if (t >= off) v += s[t - off];
        __syncthreads();
        s[t] = v;
        __syncthreads();
    }
    int run = (t == 0) ? 0 : s[t - 1];
    if (2 * t     < NBUCK) bstart[2 * t]     = run;
    if (2 * t + 1 < NBUCK) bstart[2 * t + 1] = run + a0;
    if (t == 0) bstart[NBUCK] = E;
}

__global__ __launch_bounds__(512) void scatter_kernel(
    const int* __restrict__ ei, int E,
    const int* __restrict__ bstart,
    const int* __restrict__ blkhist,
    int* __restrict__ packed,
    const int* __restrict__ flags)
{
    __shared__ int cur[NBUCK];
    int tid = threadIdx.x;
    long obase = (long)blockIdx.x * NBUCK;
    for (int i = tid; i < NBUCK; i += 512) cur[i] = bstart[i] + blkhist[obase + i];
    __syncthreads();
    int is64 = flags[1];
    long e0 = (long)blockIdx.x * SCHUNK;
    long e1 = e0 + SCHUNK; if (e1 > E) e1 = E;
    for (long j = e0 + tid; j < e1; j += 512) {
        int s = ldidx(ei, j, is64);
        int d = ldidx(ei, (long)E + j, is64);
        int b = d >> BSHIFT;
        int pos = atomicAdd(&cur[b], 1);
        packed[pos] = (s << BSHIFT) | (d & ((1 << BSHIFT) - 1));
    }
}

__global__ __launch_bounds__(256) void finefill_kernel(
    const int* __restrict__ bstart,
    const int* __restrict__ packed,
    int* __restrict__ rowptr,
    int* __restrict__ cnt,
    int* __restrict__ srclist)
{
    __shared__ int lcnt[1 << BSHIFT];
    __shared__ int lsum[256];
    int b = blockIdx.x;
    int tid = threadIdx.x;
    int nbase = b << BSHIFT;
    int beg = bstart[b];
    int end = bstart[b + 1];

    for (int i = tid; i < (1 << BSHIFT); i += 256) lcnt[i] = 0;
    __syncthreads();

    for (int j = beg + tid; j < end; j += 256)
        atomicAdd(&lcnt[packed[j] & ((1 << BSHIFT) - 1)], 1);
    __syncthreads();

    int i0 = tid * 4;
    int c0 = lcnt[i0], c1 = lcnt[i0 + 1], c2 = lcnt[i0 + 2], c3 = lcnt[i0 + 3];
    lsum[tid] = c0 + c1 + c2 + c3;
    __syncthreads();
    for (int off = 1; off < 256; off <<= 1) {
        int v = lsum[tid];
        if (tid >= off) v += lsum[tid - off];
        __syncthreads();
        lsum[tid] = v;
        __syncthreads();
    }
    int run = beg + ((tid == 0) ? 0 : lsum[tid - 1]);
    int r0 = run, r1 = r0 + c0, r2 = r1 + c1, r3 = r2 + c2;

    int n0 = nbase + i0;
    if (n0     < NT) { rowptr[n0]     = r0; cnt[n0]     = c0; }
    if (n0 + 1 < NT) { rowptr[n0 + 1] = r1; cnt[n0 + 1] = c1; }
    if (n0 + 2 < NT) { rowptr[n0 + 2] = r2; cnt[n0 + 2] = c2; }
    if (n0 + 3 < NT) { rowptr[n0 + 3] = r3; cnt[n0 + 3] = c3; }

    lcnt[i0] = r0; lcnt[i0 + 1] = r1; lcnt[i0 + 2] = r2; lcnt[i0 + 3] = r3;
    __syncthreads();

    for (int j = beg + tid; j < end; j += 256) {
        int p = packed[j];
        int dl = p & ((1 << BSHIFT) - 1);
        int pos = atomicAdd(&lcnt[dl], 1);
        srclist[pos] = p >> BSHIFT;
    }
}

// ---------------- fused SAGE layer (R5-proven config, verbatim):
// 512 threads = 8 waves per 64-node tile. Weights + means staged in LDS with
// 144B padded rows (conflict-free ds_read_b128); weight-stage latency hides
// under the gather loop. Gather: 8 lanes/node x 8 nodes/wave, UNPREDICATED
// 8-deep 16B load pipeline. Combine: wave (w&3, w>>2) covers 16 rows x 2 h-tiles.
template <bool RELU>
__global__ __launch_bounds__(512) void sage_layer(
    const unsigned short* __restrict__ xin,
    const int* __restrict__ rowptr,
    const int* __restrict__ cnt,
    const int* __restrict__ srclist,
    const void* __restrict__ Wl,
    const void* __restrict__ bias,
    const void* __restrict__ Wr,
    unsigned short* __restrict__ xout,
    const int* __restrict__ flags)
{
    __shared__ short8 lWl8[HD * PD8];   // 64 rows x 9 slots
    __shared__ short8 lWr8[HD * PD8];
    __shared__ short8 lm8[HD * PD8];
    __shared__ float lb[HD];

    int tid = threadIdx.x;
    int isbf = flags[0];

    // stage weights global->LDS (padded layout), latency hidden under gather
    if (isbf) {
        const short8* wl8 = (const short8*)Wl;
        const short8* wr8 = (const short8*)Wr;
        int i = tid;                       // i < 512 exactly: row=i>>3, frag=i&7
        int di = (i >> 3) * PD8 + (i & 7);
        lWl8[di] = wl8[i];
        lWr8[di] = wr8[i];
    } else {
        const floatx4* wlf = (const floatx4*)Wl;
        const floatx4* wrf = (const floatx4*)Wr;
        int i = tid;
        int di = (i >> 3) * PD8 + (i & 7);
        floatx4 a = wlf[2 * i], b = wlf[2 * i + 1];
        short8 r;
        r[0]=(short)f2bf_raw(a[0]); r[1]=(short)f2bf_raw(a[1]); r[2]=(short)f2bf_raw(a[2]); r[3]=(short)f2bf_raw(a[3]);
        r[4]=(short)f2bf_raw(b[0]); r[5]=(short)f2bf_raw(b[1]); r[6]=(short)f2bf_raw(b[2]); r[7]=(short)f2bf_raw(b[3]);
        lWl8[di] = r;
        a = wrf[2 * i]; b = wrf[2 * i + 1];
        r[0]=(short)f2bf_raw(a[0]); r[1]=(short)f2bf_raw(a[1]); r[2]=(short)f2bf_raw(a[2]); r[3]=(short)f2bf_raw(a[3]);
        r[4]=(short)f2bf_raw(b[0]); r[5]=(short)f2bf_raw(b[1]); r[6]=(short)f2bf_raw(b[2]); r[7]=(short)f2bf_raw(b[3]);
        lWr8[di] = r;
    }
    if (tid < HD) lb[tid] = ldf(bias, tid, isbf);

    int tile = blockIdx.x;                 // 64 nodes per tile; NT = 64*4375 exactly
    long base = (long)tile * HD * HD;

    int w8 = tid >> 6;          // wave 0..7
    int lane = tid & 63;
    int mrow = lane & 15;
    int quad = lane >> 4;
    int roww = (w8 & 3) * 16 + mrow;   // combine row this lane serves
    int htp  = w8 >> 2;                // h-tile pair selector (0 or 1)

    // own-row MFMA A-fragments straight from global (xout != xin, no hazard)
    const short8* xrow = (const short8*)&xin[base + (long)roww * HD];
    short8 ax0 = xrow[quad];
    short8 ax1 = xrow[quad + 4];

    // ---- gather phase: 8 lanes per node, 8 nodes per wave
    int g = lane >> 3;          // node group 0..7
    int sub = lane & 7;         // 16B fragment 0..7 of the 128B row
    int nl = w8 * 8 + g;        // node local id 0..63
    int n = tile * 64 + nl;
    int beg = rowptr[n];
    int deg = cnt[n];

    float acc[8];
    #pragma unroll
    for (int k = 0; k < 8; ++k) acc[k] = 0.f;

    for (int j0 = 0; j0 < deg; j0 += 8) {
        int e = j0 + sub;
        int sv = (e < deg) ? srclist[beg + e] : 0;    // 8 coalesced ids per group
        int cq = deg - j0; if (cq > 8) cq = 8;
        short8 r[8];
        #pragma unroll
        for (int q = 0; q < 8; ++q) {                 // 8 independent 16B loads in flight
            int s = __shfl(sv, (g << 3) | q);
            r[q] = *(const short8*)&xin[(long)s * HD + sub * 8];
        }
        #pragma unroll
        for (int q = 0; q < 8; ++q) {
            if (q < cq) {
                #pragma unroll
                for (int k = 0; k < 8; ++k)
                    acc[k] += bfu2f((unsigned short)r[q][k]);
            }
        }
    }

    float rd = 1.0f / fmaxf((float)deg, 1.0f);
    short8 o;
    #pragma unroll
    for (int k = 0; k < 8; ++k) o[k] = (short)f2bf_raw(acc[k] * rd);   // same rounding as before
    lm8[nl * PD8 + sub] = o;

    __syncthreads();   // lmean + weights ready

    // ---- MFMA combine phase
    short8 am0 = lm8[roww * PD8 + quad];
    short8 am1 = lm8[roww * PD8 + 4 + quad];

    floatx4 acc4[2];
    #pragma unroll
    for (int t = 0; t < 2; ++t) {
        int h = (htp * 2 + t) * 16 + mrow;
        short8 bl0 = lWl8[h * PD8 + quad];
        short8 bl1 = lWl8[h * PD8 + 4 + quad];
        short8 br0 = lWr8[h * PD8 + quad];
        short8 br1 = lWr8[h * PD8 + 4 + quad];
        floatx4 a = {0.f, 0.f, 0.f, 0.f};
        a = __builtin_amdgcn_mfma_f32_16x16x32_bf16(am0, bl0, a, 0, 0, 0);
        a = __builtin_amdgcn_mfma_f32_16x16x32_bf16(am1, bl1, a, 0, 0, 0);
        a = __builtin_amdgcn_mfma_f32_16x16x32_bf16(ax0, br0, a, 0, 0, 0);
        a = __builtin_amdgcn_mfma_f32_16x16x32_bf16(ax1, br1, a, 0, 0, 0);
        acc4[t] = a;
    }

    #pragma unroll
    for (int t = 0; t < 2; ++t) {
        int h = (htp * 2 + t) * 16 + mrow;
        float bv = lb[h];
        #pragma unroll
        for (int r = 0; r < 4; ++r) {
            int node = (w8 & 3) * 16 + quad * 4 + r;
            float v = acc4[t][r] + bv;
            if (RELU) v = fmaxf(v, 0.0f);
            xout[base + node * HD + h] = f2bf_raw(v);
        }
    }
}

// ---------------- final: out[e] = dot(x2[u[e]], x2[NU + m[e]])
// v3: same proven 4-lane/edge mapping, unrolled 2 edges per group -> wave
// covers 32 edges with 8 independent 16B loads in flight per lane.
// EL % 32 == 0 (500000 = 32 * 15625), so no tail handling needed.
__global__ __launch_bounds__(256) void dot_kernel(
    const unsigned short* __restrict__ x2,
    const int* __restrict__ eli,
    void* __restrict__ out,
    int EL,
    const int* __restrict__ flags)
{
    int wid = (blockIdx.x * 256 + threadIdx.x) >> 6;    // global wave id
    long base = (long)wid * 32;                          // first edge of this wave
    if (base >= EL) return;
    int lane = threadIdx.x & 63;
    int isbf = flags[0];
    int is64 = flags[1];

    // lanes 0..31 load u indices for 32 edges, lanes 32..63 load m indices
    int idxv = (lane < 32) ? ldidx(eli, base + lane, is64)
                           : ldidx(eli, (long)EL + base + (lane - 32), is64);

    int e   = lane >> 2;          // edge-pair slot 0..15
    int seg = lane & 3;           // 16-element segment of the 64-dim row
    int uA = __shfl(idxv, e);
    int uB = __shfl(idxv, e + 16);
    int mA = __shfl(idxv, 32 + e);
    int mB = __shfl(idxv, 48 + e);

    const short8* upA = (const short8*)(x2 + (long)uA * HD + seg * 16);
    const short8* mpA = (const short8*)(x2 + (long)(NU + mA) * HD + seg * 16);
    const short8* upB = (const short8*)(x2 + (long)uB * HD + seg * 16);
    const short8* mpB = (const short8*)(x2 + (long)(NU + mB) * HD + seg * 16);
    short8 a0 = upA[0], a1 = upA[1];
    short8 b0 = mpA[0], b1 = mpA[1];
    short8 c0 = upB[0], c1 = upB[1];
    short8 d0 = mpB[0], d1 = mpB[1];

    float pA = 0.f, pB = 0.f;
    #pragma unroll
    for (int j = 0; j < 8; ++j) {
        pA += bfu2f((unsigned short)a0[j]) * bfu2f((unsigned short)b0[j]);
        pA += bfu2f((unsigned short)a1[j]) * bfu2f((unsigned short)b1[j]);
        pB += bfu2f((unsigned short)c0[j]) * bfu2f((unsigned short)d0[j]);
        pB += bfu2f((unsigned short)c1[j]) * bfu2f((unsigned short)d1[j]);
    }
    pA += __shfl_xor(pA, 1);
    pA += __shfl_xor(pA, 2);
    pB += __shfl_xor(pB, 1);
    pB += __shfl_xor(pB, 2);

    if (seg == 0) {
        long gA = base + e;
        long gB = base + e + 16;
        if (isbf) {
            ((unsigned short*)out)[gA] = f2bf_raw(pA);
            ((unsigned short*)out)[gB] = f2bf_raw(pB);
        } else {
            ((float*)out)[gA] = pA;
            ((float*)out)[gB] = pB;
        }
    }
}

extern "C" void kernel_launch(void* const* d_in, const int* in_sizes, int n_in,
                              void* d_out, int out_size, void* d_ws, size_t ws_size,
                              hipStream_t stream)
{
    const void* movie_x   = d_in[0];
    const void* user_emb  = d_in[1];
    const void* movie_emb = d_in[2];
    const void* lin_W     = d_in[3];
    const void* lin_b     = d_in[4];
    const void* W1l       = d_in[5];
    const void* b1        = d_in[6];
    const void* W1r       = d_in[7];
    const void* W2l       = d_in[8];
    const void* b2        = d_in[9];
    const void* W2r       = d_in[10];
    const int* ei  = (const int*)d_in[11];
    const int* eli = (const int*)d_in[12];
    int E  = in_sizes[11] / 2;
    int EL = in_sizes[12] / 2;

    const int NSB = (E + SCHUNK - 1) / SCHUNK;          // hist/scatter blocks (306)

    char* w = (char*)d_ws;
    unsigned short* xb0     = (unsigned short*)w;  w += (size_t)NT * HD * 2;  // 35.84 MB
    unsigned short* xb1     = (unsigned short*)w;  w += (size_t)NT * HD * 2;  // 35.84 MB (ping-pong)
    int*            cnt     = (int*)w;             w += (size_t)NT * 4;
    int*            rowptr  = (int*)w;             w += (size_t)NT * 4;
    int*            srclist = (int*)w;             w += (size_t)E * 4;        // 5 MB
    int*            packed  = (int*)w;             w += (size_t)E * 4;        // 5 MB
    int*            bcnt    = (int*)w;             w += (size_t)(NBUCK + 1) * 4;
    int*            bstart  = (int*)w;             w += (size_t)(NBUCK + 1) * 4;
    int*            blkhist = (int*)w;             w += (size_t)NSB * NBUCK * 4;  // ~335 KB
    int*            flags   = (int*)w;

    const int user_blocks   = (NU * HD / 8) / 256;      // 6250 exactly
    const int movie_blocks  = NM / 16;                  // 5000: 4 waves/block x 4 movies/wave
    const int tile_blocks   = NT / 64;                  // 4375 (512-thread blocks)
    const int dot_blocks    = ((EL + 31) / 32 + 3) / 4; // 3907

    probe_kernel<<<1, 64, 0, stream>>>(user_emb, ei, flags);

    prep_user<<<user_blocks, 256, 0, stream>>>(user_emb, xb0, flags);
    prep_movie<<<movie_blocks, 256, 0, stream>>>(movie_x, movie_emb, lin_W, lin_b, xb0, flags);

    // CSR build (once; reused by both layers) -- fully atomic-free global path
    blk_hist<<<NSB, 512, 0, stream>>>(ei, E, blkhist, flags);
    col_scan<<<NBUCK, 256, 0, stream>>>(blkhist, NSB, bcnt);
    bucket_scan<<<1, 256, 0, stream>>>(bcnt, bstart, E);
    scatter_kernel<<<NSB, 512, 0, stream>>>(ei, E, bstart, blkhist, packed, flags);
    finefill_kernel<<<NBUCK, 256, 0, stream>>>(bstart, packed, rowptr, cnt, srclist);

    // fused layers (ping-pong xb0 -> xb1 -> xb0)
    sage_layer<true><<<tile_blocks, 512, 0, stream>>>(xb0, rowptr, cnt, srclist, W1l, b1, W1r, xb1, flags);
    sage_layer<false><<<tile_blocks, 512, 0, stream>>>(xb1, rowptr, cnt, srclist, W2l, b2, W2r, xb0, flags);

    // final edge dot products
    dot_kernel<<<dot_blocks, 256, 0, stream>>>(xb0, eli, d_out, EL, flags);
}

// Round 10
// 302.415 us; speedup vs baseline: 1.2389x; 1.0056x over previous
//
#include <hip/hip_runtime.h>
#include <hip/hip_bf16.h>

#define NU 200000
#define NM 80000
#define NT 280000   // NU + NM
#define HD 64
#define FM 20

#define BSHIFT 10
#define NBUCK ((NT + 1023) >> 10)   // 274 buckets of 1024 nodes
#define SCHUNK 4096                 // edges per hist/scatter block
#define UBLK 6250                   // user-copy blocks in prep_nodes (NU*HD/8/256)

#define PD 72        // padded LDS row: 72 shorts = 144 B = 9 x 16B slots (odd -> conflict-free)
#define PD8 (PD / 8) // 9 short8 slots per row

typedef __attribute__((ext_vector_type(8))) short short8;
typedef __attribute__((ext_vector_type(4))) float floatx4;

__device__ __forceinline__ float bfu2f(unsigned short u) {
    union { unsigned int u; float f; } c; c.u = ((unsigned int)u) << 16; return c.f;
}

__device__ __forceinline__ unsigned short f2bf_raw(float f) {
    union { float f; unsigned int u; } c; c.f = f;
    unsigned int u = c.u + 0x7FFFu + ((c.u >> 16) & 1u);   // round-nearest-even
    return (unsigned short)(u >> 16);
}

__device__ __forceinline__ float ldf(const void* p, long i, int isbf) {
    return isbf ? bfu2f(((const unsigned short*)p)[i]) : ((const float*)p)[i];
}
__device__ __forceinline__ int ldidx(const int* p, long j, int is64) {
    return is64 ? p[2 * j] : p[j];
}

// inline dtype probes (wave-uniform; ~130 L2-hot loads, folds to SGPR via ballot)
__device__ __forceinline__ int probe_isbf(const void* user_emb, int lane) {
    int bad = 0;
    for (int i = lane; i < 128; i += 64) {
        unsigned short h = ((const unsigned short*)user_emb)[i];
        if (((h >> 7) & 0xFF) >= 135) bad = 1;   // |x| >= 256 or Inf/NaN -> not bf16
    }
    return (__ballot(bad != 0) == 0ULL) ? 1 : 0;
}
__device__ __forceinline__ int probe_is64(const int* ei, int lane) {
    int odd = 0;
    if (lane < 16 && ei[2 * lane + 1] != 0) odd = 1;
    return (__ballot(odd != 0) == 0ULL) ? 1 : 0;
}

// ---------------- prep nodes: blocks [0,UBLK) copy/convert user rows;
// blocks [UBLK, UBLK+5000) compute movie rows (wave per 4 movies, reg weights).
__global__ __launch_bounds__(256) void prep_nodes(
    const void* __restrict__ user_emb,
    const void* __restrict__ movie_x,
    const void* __restrict__ movie_emb,
    const void* __restrict__ lin_W,
    const void* __restrict__ lin_b,
    unsigned short* __restrict__ xb)
{
    int tid = threadIdx.x;
    int lane = tid & 63;
    int isbf = probe_isbf(user_emb, lane);

    if (blockIdx.x < UBLK) {
        long t = (long)blockIdx.x * 256 + tid;            // t < NU*HD/8 = 1.6M exactly
        if (isbf) {
            ((short8*)xb)[t] = ((const short8*)user_emb)[t];
        } else {
            floatx4 a = ((const floatx4*)user_emb)[2 * t];
            floatx4 b = ((const floatx4*)user_emb)[2 * t + 1];
            short8 r;
            r[0] = (short)f2bf_raw(a[0]); r[1] = (short)f2bf_raw(a[1]);
            r[2] = (short)f2bf_raw(a[2]); r[3] = (short)f2bf_raw(a[3]);
            r[4] = (short)f2bf_raw(b[0]); r[5] = (short)f2bf_raw(b[1]);
            r[6] = (short)f2bf_raw(b[2]); r[7] = (short)f2bf_raw(b[3]);
            ((short8*)xb)[t] = r;
        }
        return;
    }

    // ---- movie path
    int wave = (blockIdx.x - UBLK) * 4 + (tid >> 6);
    int m0 = __builtin_amdgcn_readfirstlane(wave << 2);   // 4 movies per wave
    if (m0 >= NM) return;

    float wr[FM];
    if (isbf) {
        const unsigned int* p = (const unsigned int*)((const unsigned short*)lin_W + (long)lane * FM);
        #pragma unroll
        for (int i = 0; i < FM / 2; ++i) {
            unsigned int u = p[i];
            wr[2 * i]     = bfu2f((unsigned short)(u & 0xFFFFu));
            wr[2 * i + 1] = bfu2f((unsigned short)(u >> 16));
        }
    } else {
        const floatx4* p = (const floatx4*)((const float*)lin_W + (long)lane * FM);
        #pragma unroll
        for (int i = 0; i < FM / 4; ++i) {
            floatx4 v = p[i];
            wr[4 * i] = v[0]; wr[4 * i + 1] = v[1]; wr[4 * i + 2] = v[2]; wr[4 * i + 3] = v[3];
        }
    }
    float bias = ldf(lin_b, lane, isbf);

    #pragma unroll
    for (int mm = 0; mm < 4; ++mm) {
        int m = m0 + mm;
        float a0 = bias + ldf(movie_emb, (long)m * HD + lane, isbf);
        float a1 = 0.f, a2 = 0.f, a3 = 0.f;
        if (isbf) {
            const unsigned int* mr = (const unsigned int*)((const unsigned short*)movie_x + (long)m * FM);
            #pragma unroll
            for (int kk = 0; kk < FM / 2; ++kk) {
                unsigned int u = mr[kk];
                float x0 = bfu2f((unsigned short)(u & 0xFFFFu));
                float x1 = bfu2f((unsigned short)(u >> 16));
                if (kk & 1) { a2 += x0 * wr[2 * kk]; a3 += x1 * wr[2 * kk + 1]; }
                else        { a0 += x0 * wr[2 * kk]; a1 += x1 * wr[2 * kk + 1]; }
            }
        } else {
            const float* mr = (const float*)movie_x + (long)m * FM;
            #pragma unroll
            for (int k = 0; k < FM; k += 4) {
                a0 += mr[k]     * wr[k];
                a1 += mr[k + 1] * wr[k + 1];
                a2 += mr[k + 2] * wr[k + 2];
                a3 += mr[k + 3] * wr[k + 3];
            }
        }
        xb[(long)(NU + m) * HD + lane] = f2bf_raw((a0 + a1) + (a2 + a3));
    }
}

// ---------------- CSR build: atomic-free scatter via 2D histogram scan ----
__global__ __launch_bounds__(512) void blk_hist(
    const int* __restrict__ ei, int E,
    int* __restrict__ blkhist)
{
    __shared__ int h[NBUCK];
    int tid = threadIdx.x;
    int is64 = probe_is64(ei, tid & 63);
    for (int i = tid; i < NBUCK; i += 512) h[i] = 0;
    __syncthreads();
    long e0 = (long)blockIdx.x * SCHUNK;
    long e1 = e0 + SCHUNK; if (e1 > E) e1 = E;
    for (long j = e0 + tid; j < e1; j += 512) {
        int d = ldidx(ei, (long)E + j, is64);
        atomicAdd(&h[d >> BSHIFT], 1);
    }
    __syncthreads();
    long obase = (long)blockIdx.x * NBUCK;
    for (int i = tid; i < NBUCK; i += 512) blkhist[obase + i] = h[i];
}

// col_scan: one block per bucket b. Exclusive prefix over blocks, in place;
// emits bucket total to bcnt[b].
__global__ __launch_bounds__(256) void col_scan(
    int* __restrict__ blkhist, int NSB,
    int* __restrict__ bcnt)
{
    __shared__ int larr[2048];
    __shared__ int lsum[256];
    int b = blockIdx.x;
    int t = threadIdx.x;
    for (int i = t; i < NSB; i += 256) larr[i] = blkhist[(long)i * NBUCK + b];
    __syncthreads();
    int C = (NSB + 255) >> 8;
    int beg = t * C;
    int end = beg + C; if (end > NSB) end = NSB; if (beg > NSB) beg = NSB;
    int s = 0;
    for (int i = beg; i < end; ++i) s += larr[i];
    lsum[t] = s;
    __syncthreads();
    for (int off = 1; off < 256; off <<= 1) {
        int v = lsum[t];
        if (t >= off) v += lsum[t - off];
        __syncthreads();
        lsum[t] = v;
        __syncthreads();
    }
    int run = (t == 0) ? 0 : lsum[t - 1];
    for (int i = beg; i < end; ++i) {
        int v = larr[i];
        blkhist[(long)i * NBUCK + b] = run;   // exclusive offset of block i in bucket b
        run += v;
    }
    if (t == 0) bcnt[b] = lsum[255];
}

// scatter: inline 512-wide scan of bcnt -> bucket bases; deterministic base per
// (block,bucket); LDS cursors only. packed entry: (src<<10) | (dst&1023).
__global__ __launch_bounds__(512) void scatter_kernel(
    const int* __restrict__ ei, int E,
    const int* __restrict__ bcnt,
    const int* __restrict__ blkhist,
    int* __restrict__ packed)
{
    __shared__ int sscan[512];
    __shared__ int cur[NBUCK];
    int tid = threadIdx.x;
    int is64 = probe_is64(ei, tid & 63);

    // inline exclusive scan of bcnt (NBUCK <= 512: 1 value/thread)
    sscan[tid] = (tid < NBUCK) ? bcnt[tid] : 0;
    __syncthreads();
    for (int off = 1; off < 512; off <<= 1) {
        int v = sscan[tid];
        if (tid >= off) v += sscan[tid - off];
        __syncthreads();
        sscan[tid] = v;
        __syncthreads();
    }
    long obase = (long)blockIdx.x * NBUCK;
    if (tid < NBUCK) {
        int bs = (tid == 0) ? 0 : sscan[tid - 1];
        cur[tid] = bs + blkhist[obase + tid];
    }
    __syncthreads();

    long e0 = (long)blockIdx.x * SCHUNK;
    long e1 = e0 + SCHUNK; if (e1 > E) e1 = E;
    for (long j = e0 + tid; j < e1; j += 512) {
        int s = ldidx(ei, j, is64);
        int d = ldidx(ei, (long)E + j, is64);
        int b = d >> BSHIFT;
        int pos = atomicAdd(&cur[b], 1);
        packed[pos] = (s << BSHIFT) | (d & ((1 << BSHIFT) - 1));
    }
}

// finefill: one block per bucket; inline scan of bcnt gives [beg,end); builds
// per-node CSR (LDS hist -> 1024-scan -> rowptr/cnt) and scatters srclist.
__global__ __launch_bounds__(256) void finefill_kernel(
    const int* __restrict__ bcnt,
    const int* __restrict__ packed,
    int* __restrict__ rowptr,
    int* __restrict__ cnt,
    int* __restrict__ srclist)
{
    __shared__ int lcnt[1 << BSHIFT];
    __shared__ int lsum[256];
    __shared__ int sb[NBUCK + 1];
    int b = blockIdx.x;
    int tid = threadIdx.x;
    int nbase = b << BSHIFT;

    // inline exclusive scan of bcnt (2 values/thread)
    int a0 = (2 * tid     < NBUCK) ? bcnt[2 * tid]     : 0;
    int a1 = (2 * tid + 1 < NBUCK) ? bcnt[2 * tid + 1] : 0;
    lsum[tid] = a0 + a1;
    __syncthreads();
    for (int off = 1; off < 256; off <<= 1) {
        int v = lsum[tid];
        if (tid >= off) v += lsum[tid - off];
        __syncthreads();
        lsum[tid] = v;
        __syncthreads();
    }
    {
        int run = (tid == 0) ? 0 : lsum[tid - 1];
        if (2 * tid     < NBUCK) sb[2 * tid]     = run;
        if (2 * tid + 1 < NBUCK) sb[2 * tid + 1] = run + a0;
        if (tid == 0) sb[NBUCK] = lsum[255];
    }
    for (int i = tid; i < (1 << BSHIFT); i += 256) lcnt[i] = 0;
    __syncthreads();
    int beg = sb[b];
    int end = sb[b + 1];

    // pass 1: in-bucket per-node histogram (LDS atomics)
    for (int j = beg + tid; j < end; j += 256)
        atomicAdd(&lcnt[packed[j] & ((1 << BSHIFT) - 1)], 1);
    __syncthreads();

    // 1024-wide exclusive scan: 4 elems/thread + 256-wide Hillis-Steele
    int i0 = tid * 4;
    int c0 = lcnt[i0], c1 = lcnt[i0 + 1], c2 = lcnt[i0 + 2], c3 = lcnt[i0 + 3];
    lsum[tid] = c0 + c1 + c2 + c3;
    __syncthreads();
    for (int off = 1; off < 256; off <<= 1) {
        int v = lsum[tid];
        if (tid >= off) v += lsum[tid - off];
        __syncthreads();
        lsum[tid] = v;
        __syncthreads();
    }
    int run = beg + ((tid == 0) ? 0 : lsum[tid - 1]);
    int r0 = run, r1 = r0 + c0, r2 = r1 + c1, r3 = r2 + c2;

    int n0 = nbase + i0;
    if (n0     < NT) { rowptr[n0]     = r0; cnt[n0]     = c0; }
    if (n0 + 1 < NT) { rowptr[n0 + 1] = r1; cnt[n0 + 1] = c1; }
    if (n0 + 2 < NT) { rowptr[n0 + 2] = r2; cnt[n0 + 2] = c2; }
    if (n0 + 3 < NT) { rowptr[n0 + 3] = r3; cnt[n0 + 3] = c3; }

    lcnt[i0] = r0; lcnt[i0 + 1] = r1; lcnt[i0 + 2] = r2; lcnt[i0 + 3] = r3;
    __syncthreads();

    // pass 2: scatter src ids (stores confined to this bucket's srclist range)
    for (int j = beg + tid; j < end; j += 256) {
        int p = packed[j];
        int dl = p & ((1 << BSHIFT) - 1);
        int pos = atomicAdd(&lcnt[dl], 1);
        srclist[pos] = p >> BSHIFT;
    }
}

// ---------------- fused SAGE layer (R5-proven config):
// 512 threads = 8 waves per 64-node tile. Weights + means staged in LDS with
// 144B padded rows (conflict-free ds_read_b128); weight-stage latency hides
// under the gather loop. Gather: 8 lanes/node x 8 nodes/wave, UNPREDICATED
// 8-deep 16B load pipeline. Combine: wave (w&3, w>>2) covers 16 rows x 2 h-tiles.
template <bool RELU>
__global__ __launch_bounds__(512) void sage_layer(
    const unsigned short* __restrict__ xin,
    const int* __restrict__ rowptr,
    const int* __restrict__ cnt,
    const int* __restrict__ srclist,
    const void* __restrict__ Wl,
    const void* __restrict__ bias,
    const void* __restrict__ Wr,
    unsigned short* __restrict__ xout,
    const void* __restrict__ uprobe)
{
    __shared__ short8 lWl8[HD * PD8];   // 64 rows x 9 slots
    __shared__ short8 lWr8[HD * PD8];
    __shared__ short8 lm8[HD * PD8];
    __shared__ float lb[HD];

    int tid = threadIdx.x;
    int lane = tid & 63;
    int isbf = probe_isbf(uprobe, lane);

    // stage weights global->LDS (padded layout), latency hidden under gather
    if (isbf) {
        const short8* wl8 = (const short8*)Wl;
        const short8* wr8 = (const short8*)Wr;
        int i = tid;                       // i < 512 exactly: row=i>>3, frag=i&7
        int di = (i >> 3) * PD8 + (i & 7);
        lWl8[di] = wl8[i];
        lWr8[di] = wr8[i];
    } else {
        const floatx4* wlf = (const floatx4*)Wl;
        const floatx4* wrf = (const floatx4*)Wr;
        int i = tid;
        int di = (i >> 3) * PD8 + (i & 7);
        floatx4 a = wlf[2 * i], b = wlf[2 * i + 1];
        short8 r;
        r[0]=(short)f2bf_raw(a[0]); r[1]=(short)f2bf_raw(a[1]); r[2]=(short)f2bf_raw(a[2]); r[3]=(short)f2bf_raw(a[3]);
        r[4]=(short)f2bf_raw(b[0]); r[5]=(short)f2bf_raw(b[1]); r[6]=(short)f2bf_raw(b[2]); r[7]=(short)f2bf_raw(b[3]);
        lWl8[di] = r;
        a = wrf[2 * i]; b = wrf[2 * i + 1];
        r[0]=(short)f2bf_raw(a[0]); r[1]=(short)f2bf_raw(a[1]); r[2]=(short)f2bf_raw(a[2]); r[3]=(short)f2bf_raw(a[3]);
        r[4]=(short)f2bf_raw(b[0]); r[5]=(short)f2bf_raw(b[1]); r[6]=(short)f2bf_raw(b[2]); r[7]=(short)f2bf_raw(b[3]);
        lWr8[di] = r;
    }
    if (tid < HD) lb[tid] = ldf(bias, tid, isbf);

    int tile = blockIdx.x;                 // 64 nodes per tile; NT = 64*4375 exactly
    long base = (long)tile * HD * HD;

    int w8 = tid >> 6;          // wave 0..7
    int mrow = lane & 15;
    int quad = lane >> 4;
    int roww = (w8 & 3) * 16 + mrow;   // combine row this lane serves
    int htp  = w8 >> 2;                // h-tile pair selector (0 or 1)

    // own-row MFMA A-fragments straight from global (xout != xin, no hazard)
    const short8* xrow = (const short8*)&xin[base + (long)roww * HD];
    short8 ax0 = xrow[quad];
    short8 ax1 = xrow[quad + 4];

    // ---- gather phase: 8 lanes per node, 8 nodes per wave
    int g = lane >> 3;          // node group 0..7
    int sub = lane & 7;         // 16B fragment 0..7 of the 128B row
    int nl = w8 * 8 + g;        // node local id 0..63
    int n = tile * 64 + nl;
    int beg = rowptr[n];
    int deg = cnt[n];

    float acc[8];
    #pragma unroll
    for (int k = 0; k < 8; ++k) acc[k] = 0.f;

    for (int j0 = 0; j0 < deg; j0 += 8) {
        int e = j0 + sub;
        int sv = (e < deg) ? srclist[beg + e] : 0;    // 8 coalesced ids per group
        int cq = deg - j0; if (cq > 8) cq = 8;
        short8 r[8];
        #pragma unroll
        for (int q = 0; q < 8; ++q) {                 // 8 independent 16B loads in flight
            int s = __shfl(sv, (g << 3) | q);
            r[q] = *(const short8*)&xin[(long)s * HD + sub * 8];
        }
        #pragma unroll
        for (int q = 0; q < 8; ++q) {
            if (q < cq) {
                #pragma unroll
                for (int k = 0; k < 8; ++k)
                    acc[k] += bfu2f((unsigned short)r[q][k]);
            }
        }
    }

    float rd = 1.0f / fmaxf((float)deg, 1.0f);
    short8 o;
    #pragma unroll
    for (int k = 0; k < 8; ++k) o[k] = (short)f2bf_raw(acc[k] * rd);   // same rounding as before
    lm8[nl * PD8 + sub] = o;

    __syncthreads();   // lmean + weights ready

    // ---- MFMA combine phase
    short8 am0 = lm8[roww * PD8 + quad];
    short8 am1 = lm8[roww * PD8 + 4 + quad];

    floatx4 acc4[2];
    #pragma unroll
    for (int t = 0; t < 2; ++t) {
        int h = (htp * 2 + t) * 16 + mrow;
        short8 bl0 = lWl8[h * PD8 + quad];
        short8 bl1 = lWl8[h * PD8 + 4 + quad];
        short8 br0 = lWr8[h * PD8 + quad];
        short8 br1 = lWr8[h * PD8 + 4 + quad];
        floatx4 a = {0.f, 0.f, 0.f, 0.f};
        a = __builtin_amdgcn_mfma_f32_16x16x32_bf16(am0, bl0, a, 0, 0, 0);
        a = __builtin_amdgcn_mfma_f32_16x16x32_bf16(am1, bl1, a, 0, 0, 0);
        a = __builtin_amdgcn_mfma_f32_16x16x32_bf16(ax0, br0, a, 0, 0, 0);
        a = __builtin_amdgcn_mfma_f32_16x16x32_bf16(ax1, br1, a, 0, 0, 0);
        acc4[t] = a;
    }

    #pragma unroll
    for (int t = 0; t < 2; ++t) {
        int h = (htp * 2 + t) * 16 + mrow;
        float bv = lb[h];
        #pragma unroll
        for (int r = 0; r < 4; ++r) {
            int node = (w8 & 3) * 16 + quad * 4 + r;
            float v = acc4[t][r] + bv;
            if (RELU) v = fmaxf(v, 0.0f);
            xout[base + node * HD + h] = f2bf_raw(v);
        }
    }
}

// ---------------- final: out[e] = dot(x2[u[e]], x2[NU + m[e]])
// 4-lane/edge mapping, 2 edges unrolled per group -> 32 edges/wave.
// EL % 32 == 0 (500000 = 32 * 15625): no tail handling needed.
__global__ __launch_bounds__(256) void dot_kernel(
    const unsigned short* __restrict__ x2,
    const int* __restrict__ eli,
    void* __restrict__ out,
    int EL,
    const int* __restrict__ ei,
    const void* __restrict__ uprobe)
{
    int lane = threadIdx.x & 63;
    int isbf = probe_isbf(uprobe, lane);
    int is64 = probe_is64(ei, lane);

    int wid = (blockIdx.x * 256 + threadIdx.x) >> 6;    // global wave id
    long base = (long)wid * 32;                          // first edge of this wave
    if (base >= EL) return;

    // lanes 0..31 load u indices for 32 edges, lanes 32..63 load m indices
    int idxv = (lane < 32) ? ldidx(eli, base + lane, is64)
                           : ldidx(eli, (long)EL + base + (lane - 32), is64);

    int e   = lane >> 2;          // edge-pair slot 0..15
    int seg = lane & 3;           // 16-element segment of the 64-dim row
    int uA = __shfl(idxv, e);
    int uB = __shfl(idxv, e + 16);
    int mA = __shfl(idxv, 32 + e);
    int mB = __shfl(idxv, 48 + e);

    const short8* upA = (const short8*)(x2 + (long)uA * HD + seg * 16);
    const short8* mpA = (const short8*)(x2 + (long)(NU + mA) * HD + seg * 16);
    const short8* upB = (const short8*)(x2 + (long)uB * HD + seg * 16);
    const short8* mpB = (const short8*)(x2 + (long)(NU + mB) * HD + seg * 16);
    short8 a0 = upA[0], a1 = upA[1];
    short8 b0 = mpA[0], b1 = mpA[1];
    short8 c0 = upB[0], c1 = upB[1];
    short8 d0 = mpB[0], d1 = mpB[1];

    float pA = 0.f, pB = 0.f;
    #pragma unroll
    for (int j = 0; j < 8; ++j) {
        pA += bfu2f((unsigned short)a0[j]) * bfu2f((unsigned short)b0[j]);
        pA += bfu2f((unsigned short)a1[j]) * bfu2f((unsigned short)b1[j]);
        pB += bfu2f((unsigned short)c0[j]) * bfu2f((unsigned short)d0[j]);
        pB += bfu2f((unsigned short)c1[j]) * bfu2f((unsigned short)d1[j]);
    }
    pA += __shfl_xor(pA, 1);
    pA += __shfl_xor(pA, 2);
    pB += __shfl_xor(pB, 1);
    pB += __shfl_xor(pB, 2);

    if (seg == 0) {
        long gA = base + e;
        long gB = base + e + 16;
        if (isbf) {
            ((unsigned short*)out)[gA] = f2bf_raw(pA);
            ((unsigned short*)out)[gB] = f2bf_raw(pB);
        } else {
            ((float*)out)[gA] = pA;
            ((float*)out)[gB] = pB;
        }
    }
}

extern "C" void kernel_launch(void* const* d_in, const int* in_sizes, int n_in,
                              void* d_out, int out_size, void* d_ws, size_t ws_size,
                              hipStream_t stream)
{
    const void* movie_x   = d_in[0];
    const void* user_emb  = d_in[1];
    const void* movie_emb = d_in[2];
    const void* lin_W     = d_in[3];
    const void* lin_b     = d_in[4];
    const void* W1l       = d_in[5];
    const void* b1        = d_in[6];
    const void* W1r       = d_in[7];
    const void* W2l       = d_in[8];
    const void* b2        = d_in[9];
    const void* W2r       = d_in[10];
    const int* ei  = (const int*)d_in[11];
    const int* eli = (const int*)d_in[12];
    int E  = in_sizes[11] / 2;
    int EL = in_sizes[12] / 2;

    const int NSB = (E + SCHUNK - 1) / SCHUNK;          // hist/scatter blocks (306)

    char* w = (char*)d_ws;
    unsigned short* xb0     = (unsigned short*)w;  w += (size_t)NT * HD * 2;  // 35.84 MB
    unsigned short* xb1     = (unsigned short*)w;  w += (size_t)NT * HD * 2;  // 35.84 MB (ping-pong)
    int*            cnt     = (int*)w;             w += (size_t)NT * 4;
    int*            rowptr  = (int*)w;             w += (size_t)NT * 4;
    int*            srclist = (int*)w;             w += (size_t)E * 4;        // 5 MB
    int*            packed  = (int*)w;             w += (size_t)E * 4;        // 5 MB
    int*            bcnt    = (int*)w;             w += (size_t)(NBUCK + 1) * 4;
    int*            blkhist = (int*)w;             w += (size_t)NSB * NBUCK * 4;  // ~335 KB

    const int node_blocks   = UBLK + NM / 16;           // 6250 user + 5000 movie
    const int tile_blocks   = NT / 64;                  // 4375 (512-thread blocks)
    const int dot_blocks    = ((EL + 31) / 32 + 3) / 4; // 3907

    // node features (users copied, movies computed)
    prep_nodes<<<node_blocks, 256, 0, stream>>>(user_emb, movie_x, movie_emb, lin_W, lin_b, xb0);

    // CSR build (once; reused by both layers) -- fully atomic-free global path
    blk_hist<<<NSB, 512, 0, stream>>>(ei, E, blkhist);
    col_scan<<<NBUCK, 256, 0, stream>>>(blkhist, NSB, bcnt);
    scatter_kernel<<<NSB, 512, 0, stream>>>(ei, E, bcnt, blkhist, packed);
    finefill_kernel<<<NBUCK, 256, 0, stream>>>(bcnt, packed, rowptr, cnt, srclist);

    // fused layers (ping-pong xb0 -> xb1 -> xb0)
    sage_layer<true><<<tile_blocks, 512, 0, stream>>>(xb0, rowptr, cnt, srclist, W1l, b1, W1r, xb1, user_emb);
    sage_layer<false><<<tile_blocks, 512, 0, stream>>>(xb1, rowptr, cnt, srclist, W2l, b2, W2r, xb0, user_emb);

    // final edge dot products
    dot_kernel<<<dot_blocks, 256, 0, stream>>>(xb0, eli, d_out, EL, ei, user_emb);
}

// Round 11
// 293.346 us; speedup vs baseline: 1.2772x; 1.0309x over previous
//
#include <hip/hip_runtime.h>
#include <hip/hip_bf16.h>

#define NU 200000
#define NM 80000
#define NT 280000   // NU + NM
#define HD 64
#define FM 20

#define BSHIFT 10
#define NBUCK ((NT + 1023) >> 10)   // 274 buckets of 1024 nodes
#define SCHUNK 4096                 // edges per hist/scatter block
#define UBLK 6250                   // user-copy blocks in prep_nodes (NU*HD/8/256)

#define PD 72        // padded LDS row: 72 shorts = 144 B = 9 x 16B slots (odd -> conflict-free)
#define PD8 (PD / 8) // 9 short8 slots per row

typedef __attribute__((ext_vector_type(8))) short short8;
typedef __attribute__((ext_vector_type(4))) float floatx4;
typedef __attribute__((ext_vector_type(4))) unsigned int uint4v;
typedef __attribute__((ext_vector_type(2))) float float2v;

__device__ __forceinline__ float bfu2f(unsigned short u) {
    union { unsigned int u; float f; } c; c.u = ((unsigned int)u) << 16; return c.f;
}

__device__ __forceinline__ unsigned short f2bf_raw(float f) {
    union { float f; unsigned int u; } c; c.f = f;
    unsigned int u = c.u + 0x7FFFu + ((c.u >> 16) & 1u);   // round-nearest-even
    return (unsigned short)(u >> 16);
}

__device__ __forceinline__ float ldf(const void* p, long i, int isbf) {
    return isbf ? bfu2f(((const unsigned short*)p)[i]) : ((const float*)p)[i];
}
__device__ __forceinline__ int ldidx(const int* p, long j, int is64) {
    return is64 ? p[2 * j] : p[j];
}

// ---------------- prep nodes: blocks [0,UBLK) copy/convert user rows;
// blocks [UBLK, UBLK+5000) compute movie rows. Block 0 also publishes flags
// (isbf16, isint64) to workspace for all downstream kernels (stream-ordered).
__global__ __launch_bounds__(256) void prep_nodes(
    const void* __restrict__ user_emb,
    const void* __restrict__ movie_x,
    const void* __restrict__ movie_emb,
    const void* __restrict__ lin_W,
    const void* __restrict__ lin_b,
    const int* __restrict__ ei,
    unsigned short* __restrict__ xb,
    int* __restrict__ flags)
{
    int tid = threadIdx.x;
    int lane = tid & 63;

    // inline dtype probe (wave-uniform, L2-hot)
    int bad = 0;
    for (int i = lane; i < 128; i += 64) {
        unsigned short h = ((const unsigned short*)user_emb)[i];
        if (((h >> 7) & 0xFF) >= 135) bad = 1;
    }
    int isbf = (__ballot(bad != 0) == 0ULL) ? 1 : 0;

    if (blockIdx.x == 0 && tid < 64) {
        int odd = 0;
        if (lane < 16 && ei[2 * lane + 1] != 0) odd = 1;
        int is64 = (__ballot(odd != 0) == 0ULL) ? 1 : 0;
        if (lane == 0) { flags[0] = isbf; flags[1] = is64; }
    }

    if (blockIdx.x < UBLK) {
        long t = (long)blockIdx.x * 256 + tid;            // t < NU*HD/8 = 1.6M exactly
        if (isbf) {
            ((short8*)xb)[t] = ((const short8*)user_emb)[t];
        } else {
            floatx4 a = ((const floatx4*)user_emb)[2 * t];
            floatx4 b = ((const floatx4*)user_emb)[2 * t + 1];
            short8 r;
            r[0] = (short)f2bf_raw(a[0]); r[1] = (short)f2bf_raw(a[1]);
            r[2] = (short)f2bf_raw(a[2]); r[3] = (short)f2bf_raw(a[3]);
            r[4] = (short)f2bf_raw(b[0]); r[5] = (short)f2bf_raw(b[1]);
            r[6] = (short)f2bf_raw(b[2]); r[7] = (short)f2bf_raw(b[3]);
            ((short8*)xb)[t] = r;
        }
        return;
    }

    // ---- movie path
    int wave = (blockIdx.x - UBLK) * 4 + (tid >> 6);
    int m0 = __builtin_amdgcn_readfirstlane(wave << 2);   // 4 movies per wave
    if (m0 >= NM) return;

    float wr[FM];
    if (isbf) {
        const unsigned int* p = (const unsigned int*)((const unsigned short*)lin_W + (long)lane * FM);
        #pragma unroll
        for (int i = 0; i < FM / 2; ++i) {
            unsigned int u = p[i];
            wr[2 * i]     = bfu2f((unsigned short)(u & 0xFFFFu));
            wr[2 * i + 1] = bfu2f((unsigned short)(u >> 16));
        }
    } else {
        const floatx4* p = (const floatx4*)((const float*)lin_W + (long)lane * FM);
        #pragma unroll
        for (int i = 0; i < FM / 4; ++i) {
            floatx4 v = p[i];
            wr[4 * i] = v[0]; wr[4 * i + 1] = v[1]; wr[4 * i + 2] = v[2]; wr[4 * i + 3] = v[3];
        }
    }
    float bias = ldf(lin_b, lane, isbf);

    #pragma unroll
    for (int mm = 0; mm < 4; ++mm) {
        int m = m0 + mm;
        float a0 = bias + ldf(movie_emb, (long)m * HD + lane, isbf);
        float a1 = 0.f, a2 = 0.f, a3 = 0.f;
        if (isbf) {
            const unsigned int* mr = (const unsigned int*)((const unsigned short*)movie_x + (long)m * FM);
            #pragma unroll
            for (int kk = 0; kk < FM / 2; ++kk) {
                unsigned int u = mr[kk];
                float x0 = bfu2f((unsigned short)(u & 0xFFFFu));
                float x1 = bfu2f((unsigned short)(u >> 16));
                if (kk & 1) { a2 += x0 * wr[2 * kk]; a3 += x1 * wr[2 * kk + 1]; }
                else        { a0 += x0 * wr[2 * kk]; a1 += x1 * wr[2 * kk + 1]; }
            }
        } else {
            const float* mr = (const float*)movie_x + (long)m * FM;
            #pragma unroll
            for (int k = 0; k < FM; k += 4) {
                a0 += mr[k]     * wr[k];
                a1 += mr[k + 1] * wr[k + 1];
                a2 += mr[k + 2] * wr[k + 2];
                a3 += mr[k + 3] * wr[k + 3];
            }
        }
        xb[(long)(NU + m) * HD + lane] = f2bf_raw((a0 + a1) + (a2 + a3));
    }
}

// ---------------- CSR build: atomic-free scatter via 2D histogram scan ----
__global__ __launch_bounds__(512) void blk_hist(
    const int* __restrict__ ei, int E,
    int* __restrict__ blkhist,
    const int* __restrict__ flags)
{
    __shared__ int h[NBUCK];
    int tid = threadIdx.x;
    int is64 = flags[1];
    for (int i = tid; i < NBUCK; i += 512) h[i] = 0;
    __syncthreads();
    long e0 = (long)blockIdx.x * SCHUNK;
    long e1 = e0 + SCHUNK; if (e1 > E) e1 = E;
    for (long j = e0 + tid; j < e1; j += 512) {
        int d = ldidx(ei, (long)E + j, is64);
        atomicAdd(&h[d >> BSHIFT], 1);
    }
    __syncthreads();
    long obase = (long)blockIdx.x * NBUCK;
    for (int i = tid; i < NBUCK; i += 512) blkhist[obase + i] = h[i];
}

// col_scan: one block per bucket b. Exclusive prefix over blocks, in place;
// emits bucket total to bcnt[b].
__global__ __launch_bounds__(256) void col_scan(
    int* __restrict__ blkhist, int NSB,
    int* __restrict__ bcnt)
{
    __shared__ int larr[2048];
    __shared__ int lsum[256];
    int b = blockIdx.x;
    int t = threadIdx.x;
    for (int i = t; i < NSB; i += 256) larr[i] = blkhist[(long)i * NBUCK + b];
    __syncthreads();
    int C = (NSB + 255) >> 8;
    int beg = t * C;
    int end = beg + C; if (end > NSB) end = NSB; if (beg > NSB) beg = NSB;
    int s = 0;
    for (int i = beg; i < end; ++i) s += larr[i];
    lsum[t] = s;
    __syncthreads();
    for (int off = 1; off < 256; off <<= 1) {
        int v = lsum[t];
        if (t >= off) v += lsum[t - off];
        __syncthreads();
        lsum[t] = v;
        __syncthreads();
    }
    int run = (t == 0) ? 0 : lsum[t - 1];
    for (int i = beg; i < end; ++i) {
        int v = larr[i];
        blkhist[(long)i * NBUCK + b] = run;   // exclusive offset of block i in bucket b
        run += v;
    }
    if (t == 0) bcnt[b] = lsum[255];
}

// scatter v2: stage edges in registers, LDS-order by bucket, then flush
// linearly so global writes are sequential within each ~15-int bucket run
// (vs 64 scattered 4B stores per wave). packed entry: (src<<10)|(dst&1023).
__global__ __launch_bounds__(512) void scatter_kernel(
    const int* __restrict__ ei, int E,
    const int* __restrict__ bcnt,
    const int* __restrict__ blkhist,
    int* __restrict__ packed,
    const int* __restrict__ flags)
{
    __shared__ int sscan[512];
    __shared__ int gb[NBUCK];        // global dest base for this block's run in bucket b
    __shared__ int lbase[NBUCK];     // local exclusive offset of bucket b
    __shared__ int lcur[NBUCK];      // hist, then running cursor
    __shared__ int lpk[SCHUNK];      // packed entries ordered by bucket
    __shared__ short lbk[SCHUNK];    // bucket id per slot

    int tid = threadIdx.x;
    int is64 = flags[1];
    long e0 = (long)blockIdx.x * SCHUNK;
    int n = (int)(((long)E - e0 < SCHUNK) ? ((long)E - e0) : SCHUNK);

    for (int i = tid; i < NBUCK; i += 512) lcur[i] = 0;
    __syncthreads();

    // pass 1: read up to 8 edges into registers + LDS histogram
    int s[8], d[8];
    #pragma unroll
    for (int k = 0; k < 8; ++k) {
        int j = tid + k * 512;
        if (j < n) {
            s[k] = ldidx(ei, e0 + j, is64);
            d[k] = ldidx(ei, (long)E + e0 + j, is64);
            atomicAdd(&lcur[d[k] >> BSHIFT], 1);
        }
    }
    __syncthreads();

    // bucket global bases: exclusive scan of bcnt (1 value/thread, NBUCK<=512)
    sscan[tid] = (tid < NBUCK) ? bcnt[tid] : 0;
    __syncthreads();
    for (int off = 1; off < 512; off <<= 1) {
        int v = sscan[tid];
        if (tid >= off) v += sscan[tid - off];
        __syncthreads();
        sscan[tid] = v;
        __syncthreads();
    }
    long obase = (long)blockIdx.x * NBUCK;
    if (tid < NBUCK)
        gb[tid] = ((tid == 0) ? 0 : sscan[tid - 1]) + blkhist[obase + tid];
    __syncthreads();

    // local exclusive scan of the block histogram
    int c = (tid < NBUCK) ? lcur[tid] : 0;
    sscan[tid] = c;
    __syncthreads();
    for (int off = 1; off < 512; off <<= 1) {
        int v = sscan[tid];
        if (tid >= off) v += sscan[tid - off];
        __syncthreads();
        sscan[tid] = v;
        __syncthreads();
    }
    if (tid < NBUCK) {
        int ex = (tid == 0) ? 0 : sscan[tid - 1];
        lbase[tid] = ex;
        lcur[tid] = ex;
    }
    __syncthreads();

    // pass 2: place entries into LDS ordered by bucket
    #pragma unroll
    for (int k = 0; k < 8; ++k) {
        int j = tid + k * 512;
        if (j < n) {
            int b = d[k] >> BSHIFT;
            int pos = atomicAdd(&lcur[b], 1);
            lpk[pos] = (s[k] << BSHIFT) | (d[k] & ((1 << BSHIFT) - 1));
            lbk[pos] = (short)b;
        }
    }
    __syncthreads();

    // flush: consecutive LDS slots within a bucket -> consecutive global addrs
    for (int i = tid; i < n; i += 512) {
        int b = lbk[i];
        packed[gb[b] + (i - lbase[b])] = lpk[i];
    }
}

// finefill: one block per bucket; inline scan of bcnt gives [beg,end); builds
// per-node CSR (LDS hist -> 1024-scan -> rowptr/cnt) and scatters srclist.
__global__ __launch_bounds__(256) void finefill_kernel(
    const int* __restrict__ bcnt,
    const int* __restrict__ packed,
    int* __restrict__ rowptr,
    int* __restrict__ cnt,
    int* __restrict__ srclist)
{
    __shared__ int lcnt[1 << BSHIFT];
    __shared__ int lsum[256];
    __shared__ int sb[NBUCK + 1];
    int b = blockIdx.x;
    int tid = threadIdx.x;
    int nbase = b << BSHIFT;

    // inline exclusive scan of bcnt (2 values/thread)
    int a0 = (2 * tid     < NBUCK) ? bcnt[2 * tid]     : 0;
    int a1 = (2 * tid + 1 < NBUCK) ? bcnt[2 * tid + 1] : 0;
    lsum[tid] = a0 + a1;
    __syncthreads();
    for (int off = 1; off < 256; off <<= 1) {
        int v = lsum[tid];
        if (tid >= off) v += lsum[tid - off];
        __syncthreads();
        lsum[tid] = v;
        __syncthreads();
    }
    {
        int run = (tid == 0) ? 0 : lsum[tid - 1];
        if (2 * tid     < NBUCK) sb[2 * tid]     = run;
        if (2 * tid + 1 < NBUCK) sb[2 * tid + 1] = run + a0;
        if (tid == 0) sb[NBUCK] = lsum[255];
    }
    for (int i = tid; i < (1 << BSHIFT); i += 256) lcnt[i] = 0;
    __syncthreads();
    int beg = sb[b];
    int end = sb[b + 1];

    // pass 1: in-bucket per-node histogram (LDS atomics)
    for (int j = beg + tid; j < end; j += 256)
        atomicAdd(&lcnt[packed[j] & ((1 << BSHIFT) - 1)], 1);
    __syncthreads();

    // 1024-wide exclusive scan: 4 elems/thread + 256-wide Hillis-Steele
    int i0 = tid * 4;
    int c0 = lcnt[i0], c1 = lcnt[i0 + 1], c2 = lcnt[i0 + 2], c3 = lcnt[i0 + 3];
    lsum[tid] = c0 + c1 + c2 + c3;
    __syncthreads();
    for (int off = 1; off < 256; off <<= 1) {
        int v = lsum[tid];
        if (tid >= off) v += lsum[tid - off];
        __syncthreads();
        lsum[tid] = v;
        __syncthreads();
    }
    int run = beg + ((tid == 0) ? 0 : lsum[tid - 1]);
    int r0 = run, r1 = r0 + c0, r2 = r1 + c1, r3 = r2 + c2;

    int n0 = nbase + i0;
    if (n0     < NT) { rowptr[n0]     = r0; cnt[n0]     = c0; }
    if (n0 + 1 < NT) { rowptr[n0 + 1] = r1; cnt[n0 + 1] = c1; }
    if (n0 + 2 < NT) { rowptr[n0 + 2] = r2; cnt[n0 + 2] = c2; }
    if (n0 + 3 < NT) { rowptr[n0 + 3] = r3; cnt[n0 + 3] = c3; }

    lcnt[i0] = r0; lcnt[i0 + 1] = r1; lcnt[i0 + 2] = r2; lcnt[i0 + 3] = r3;
    __syncthreads();

    // pass 2: scatter src ids (stores confined to this bucket's srclist range)
    for (int j = beg + tid; j < end; j += 256) {
        int p = packed[j];
        int dl = p & ((1 << BSHIFT) - 1);
        int pos = atomicAdd(&lcnt[dl], 1);
        srclist[pos] = p >> BSHIFT;
    }
}

// ---------------- fused SAGE layer (R8-proven config; inner accumulate uses
// bit-exact packed bf16->f32 unpack: lo = u<<16, hi = u&0xFFFF0000, float2
// adds so the backend can emit v_pk_add_f32. Same values, same order.)
template <bool RELU>
__global__ __launch_bounds__(512) void sage_layer(
    const unsigned short* __restrict__ xin,
    const int* __restrict__ rowptr,
    const int* __restrict__ cnt,
    const int* __restrict__ srclist,
    const void* __restrict__ Wl,
    const void* __restrict__ bias,
    const void* __restrict__ Wr,
    unsigned short* __restrict__ xout,
    const int* __restrict__ flags)
{
    __shared__ short8 lWl8[HD * PD8];   // 64 rows x 9 slots
    __shared__ short8 lWr8[HD * PD8];
    __shared__ short8 lm8[HD * PD8];
    __shared__ float lb[HD];

    int tid = threadIdx.x;
    int isbf = flags[0];

    // stage weights global->LDS (padded layout), latency hidden under gather
    if (isbf) {
        const short8* wl8 = (const short8*)Wl;
        const short8* wr8 = (const short8*)Wr;
        int i = tid;                       // i < 512 exactly: row=i>>3, frag=i&7
        int di = (i >> 3) * PD8 + (i & 7);
        lWl8[di] = wl8[i];
        lWr8[di] = wr8[i];
    } else {
        const floatx4* wlf = (const floatx4*)Wl;
        const floatx4* wrf = (const floatx4*)Wr;
        int i = tid;
        int di = (i >> 3) * PD8 + (i & 7);
        floatx4 a = wlf[2 * i], b = wlf[2 * i + 1];
        short8 r;
        r[0]=(short)f2bf_raw(a[0]); r[1]=(short)f2bf_raw(a[1]); r[2]=(short)f2bf_raw(a[2]); r[3]=(short)f2bf_raw(a[3]);
        r[4]=(short)f2bf_raw(b[0]); r[5]=(short)f2bf_raw(b[1]); r[6]=(short)f2bf_raw(b[2]); r[7]=(short)f2bf_raw(b[3]);
        lWl8[di] = r;
        a = wrf[2 * i]; b = wrf[2 * i + 1];
        r[0]=(short)f2bf_raw(a[0]); r[1]=(short)f2bf_raw(a[1]); r[2]=(short)f2bf_raw(a[2]); r[3]=(short)f2bf_raw(a[3]);
        r[4]=(short)f2bf_raw(b[0]); r[5]=(short)f2bf_raw(b[1]); r[6]=(short)f2bf_raw(b[2]); r[7]=(short)f2bf_raw(b[3]);
        lWr8[di] = r;
    }
    if (tid < HD) lb[tid] = ldf(bias, tid, isbf);

    int tile = blockIdx.x;                 // 64 nodes per tile; NT = 64*4375 exactly
    long base = (long)tile * HD * HD;

    int w8 = tid >> 6;          // wave 0..7
    int lane = tid & 63;
    int mrow = lane & 15;
    int quad = lane >> 4;
    int roww = (w8 & 3) * 16 + mrow;   // combine row this lane serves
    int htp  = w8 >> 2;                // h-tile pair selector (0 or 1)

    // own-row MFMA A-fragments straight from global (xout != xin, no hazard)
    const short8* xrow = (const short8*)&xin[base + (long)roww * HD];
    short8 ax0 = xrow[quad];
    short8 ax1 = xrow[quad + 4];

    // ---- gather phase: 8 lanes per node, 8 nodes per wave
    int g = lane >> 3;          // node group 0..7
    int sub = lane & 7;         // 16B fragment 0..7 of the 128B row
    int nl = w8 * 8 + g;        // node local id 0..63
    int n = tile * 64 + nl;
    int beg = rowptr[n];
    int deg = cnt[n];

    float2v acc2[4];
    #pragma unroll
    for (int k = 0; k < 4; ++k) { acc2[k][0] = 0.f; acc2[k][1] = 0.f; }

    for (int j0 = 0; j0 < deg; j0 += 8) {
        int e = j0 + sub;
        int sv = (e < deg) ? srclist[beg + e] : 0;    // 8 coalesced ids per group
        int cq = deg - j0; if (cq > 8) cq = 8;
        uint4v r[8];
        #pragma unroll
        for (int q = 0; q < 8; ++q) {                 // 8 independent 16B loads in flight
            int s = __shfl(sv, (g << 3) | q);
            r[q] = *(const uint4v*)&xin[(long)s * HD + sub * 8];
        }
        #pragma unroll
        for (int q = 0; q < 8; ++q) {
            if (q < cq) {
                #pragma unroll
                for (int w = 0; w < 4; ++w) {
                    unsigned int u = r[q][w];
                    union { unsigned int u; float f; } lo, hi;
                    lo.u = u << 16;                    // == bfu2f(elem 2w)
                    hi.u = u & 0xFFFF0000u;            // == bfu2f(elem 2w+1)
                    float2v t; t[0] = lo.f; t[1] = hi.f;
                    acc2[w] += t;
                }
            }
        }
    }

    float rd = 1.0f / fmaxf((float)deg, 1.0f);
    short8 o;
    #pragma unroll
    for (int w = 0; w < 4; ++w) {
        o[2 * w]     = (short)f2bf_raw(acc2[w][0] * rd);   // same rounding as before
        o[2 * w + 1] = (short)f2bf_raw(acc2[w][1] * rd);
    }
    lm8[nl * PD8 + sub] = o;

    __syncthreads();   // lmean + weights ready

    // ---- MFMA combine phase
    short8 am0 = lm8[roww * PD8 + quad];
    short8 am1 = lm8[roww * PD8 + 4 + quad];

    floatx4 acc4[2];
    #pragma unroll
    for (int t = 0; t < 2; ++t) {
        int h = (htp * 2 + t) * 16 + mrow;
        short8 bl0 = lWl8[h * PD8 + quad];
        short8 bl1 = lWl8[h * PD8 + 4 + quad];
        short8 br0 = lWr8[h * PD8 + quad];
        short8 br1 = lWr8[h * PD8 + 4 + quad];
        floatx4 a = {0.f, 0.f, 0.f, 0.f};
        a = __builtin_amdgcn_mfma_f32_16x16x32_bf16(am0, bl0, a, 0, 0, 0);
        a = __builtin_amdgcn_mfma_f32_16x16x32_bf16(am1, bl1, a, 0, 0, 0);
        a = __builtin_amdgcn_mfma_f32_16x16x32_bf16(ax0, br0, a, 0, 0, 0);
        a = __builtin_amdgcn_mfma_f32_16x16x32_bf16(ax1, br1, a, 0, 0, 0);
        acc4[t] = a;
    }

    #pragma unroll
    for (int t = 0; t < 2; ++t) {
        int h = (htp * 2 + t) * 16 + mrow;
        float bv = lb[h];
        #pragma unroll
        for (int r = 0; r < 4; ++r) {
            int node = (w8 & 3) * 16 + quad * 4 + r;
            float v = acc4[t][r] + bv;
            if (RELU) v = fmaxf(v, 0.0f);
            xout[base + node * HD + h] = f2bf_raw(v);
        }
    }
}

// ---------------- final: out[e] = dot(x2[u[e]], x2[NU + m[e]])
// 4-lane/edge mapping, 2 edges unrolled per group -> 32 edges/wave.
// EL % 32 == 0 (500000 = 32 * 15625): no tail handling needed.
__global__ __launch_bounds__(256) void dot_kernel(
    const unsigned short* __restrict__ x2,
    const int* __restrict__ eli,
    void* __restrict__ out,
    int EL,
    const int* __restrict__ flags)
{
    int wid = (blockIdx.x * 256 + threadIdx.x) >> 6;    // global wave id
    long base = (long)wid * 32;                          // first edge of this wave
    if (base >= EL) return;
    int lane = threadIdx.x & 63;
    int isbf = flags[0];
    int is64 = flags[1];

    // lanes 0..31 load u indices for 32 edges, lanes 32..63 load m indices
    int idxv = (lane < 32) ? ldidx(eli, base + lane, is64)
                           : ldidx(eli, (long)EL + base + (lane - 32), is64);

    int e   = lane >> 2;          // edge-pair slot 0..15
    int seg = lane & 3;           // 16-element segment of the 64-dim row
    int uA = __shfl(idxv, e);
    int uB = __shfl(idxv, e + 16);
    int mA = __shfl(idxv, 32 + e);
    int mB = __shfl(idxv, 48 + e);

    const short8* upA = (const short8*)(x2 + (long)uA * HD + seg * 16);
    const short8* mpA = (const short8*)(x2 + (long)(NU + mA) * HD + seg * 16);
    const short8* upB = (const short8*)(x2 + (long)uB * HD + seg * 16);
    const short8* mpB = (const short8*)(x2 + (long)(NU + mB) * HD + seg * 16);
    short8 a0 = upA[0], a1 = upA[1];
    short8 b0 = mpA[0], b1 = mpA[1];
    short8 c0 = upB[0], c1 = upB[1];
    short8 d0 = mpB[0], d1 = mpB[1];

    float pA = 0.f, pB = 0.f;
    #pragma unroll
    for (int j = 0; j < 8; ++j) {
        pA += bfu2f((unsigned short)a0[j]) * bfu2f((unsigned short)b0[j]);
        pA += bfu2f((unsigned short)a1[j]) * bfu2f((unsigned short)b1[j]);
        pB += bfu2f((unsigned short)c0[j]) * bfu2f((unsigned short)d0[j]);
        pB += bfu2f((unsigned short)c1[j]) * bfu2f((unsigned short)d1[j]);
    }
    pA += __shfl_xor(pA, 1);
    pA += __shfl_xor(pA, 2);
    pB += __shfl_xor(pB, 1);
    pB += __shfl_xor(pB, 2);

    if (seg == 0) {
        long gA = base + e;
        long gB = base + e + 16;
        if (isbf) {
            ((unsigned short*)out)[gA] = f2bf_raw(pA);
            ((unsigned short*)out)[gB] = f2bf_raw(pB);
        } else {
            ((float*)out)[gA] = pA;
            ((float*)out)[gB] = pB;
        }
    }
}

extern "C" void kernel_launch(void* const* d_in, const int* in_sizes, int n_in,
                              void* d_out, int out_size, void* d_ws, size_t ws_size,
                              hipStream_t stream)
{
    const void* movie_x   = d_in[0];
    const void* user_emb  = d_in[1];
    const void* movie_emb = d_in[2];
    const void* lin_W     = d_in[3];
    const void* lin_b     = d_in[4];
    const void* W1l       = d_in[5];
    const void* b1        = d_in[6];
    const void* W1r       = d_in[7];
    const void* W2l       = d_in[8];
    const void* b2        = d_in[9];
    const void* W2r       = d_in[10];
    const int* ei  = (const int*)d_in[11];
    const int* eli = (const int*)d_in[12];
    int E  = in_sizes[11] / 2;
    int EL = in_sizes[12] / 2;

    const int NSB = (E + SCHUNK - 1) / SCHUNK;          // hist/scatter blocks (306)

    char* w = (char*)d_ws;
    unsigned short* xb0     = (unsigned short*)w;  w += (size_t)NT * HD * 2;  // 35.84 MB
    unsigned short* xb1     = (unsigned short*)w;  w += (size_t)NT * HD * 2;  // 35.84 MB (ping-pong)
    int*            cnt     = (int*)w;             w += (size_t)NT * 4;
    int*            rowptr  = (int*)w;             w += (size_t)NT * 4;
    int*            srclist = (int*)w;             w += (size_t)E * 4;        // 5 MB
    int*            packed  = (int*)w;             w += (size_t)E * 4;        // 5 MB
    int*            bcnt    = (int*)w;             w += (size_t)(NBUCK + 1) * 4;
    int*            blkhist = (int*)w;             w += (size_t)NSB * NBUCK * 4;  // ~335 KB
    int*            flags   = (int*)w;

    const int node_blocks   = UBLK + NM / 16;           // 6250 user + 5000 movie
    const int tile_blocks   = NT / 64;                  // 4375 (512-thread blocks)
    const int dot_blocks    = ((EL + 31) / 32 + 3) / 4; // 3907

    // node features (users copied, movies computed); block 0 publishes flags
    prep_nodes<<<node_blocks, 256, 0, stream>>>(user_emb, movie_x, movie_emb, lin_W, lin_b, ei, xb0, flags);

    // CSR build (once; reused by both layers) -- fully atomic-free global path
    blk_hist<<<NSB, 512, 0, stream>>>(ei, E, blkhist, flags);
    col_scan<<<NBUCK, 256, 0, stream>>>(blkhist, NSB, bcnt);
    scatter_kernel<<<NSB, 512, 0, stream>>>(ei, E, bcnt, blkhist, packed, flags);
    finefill_kernel<<<NBUCK, 256, 0, stream>>>(bcnt, packed, rowptr, cnt, srclist);

    // fused layers (ping-pong xb0 -> xb1 -> xb0)
    sage_layer<true><<<tile_blocks, 512, 0, stream>>>(xb0, rowptr, cnt, srclist, W1l, b1, W1r, xb1, flags);
    sage_layer<false><<<tile_blocks, 512, 0, stream>>>(xb1, rowptr, cnt, srclist, W2l, b2, W2r, xb0, flags);

    // final edge dot products
    dot_kernel<<<dot_blocks, 256, 0, stream>>>(xb0, eli, d_out, EL, flags);
}